// Round 1
// baseline (804.901 us; speedup 1.0000x reference)
//
#include <hip/hip_runtime.h>
#include <hip/hip_bf16.h>

// Problem constants (fixed by the reference)
#define N_NODES 4096
#define N_EDGES 32768
#define BATCH   1024
#define NFEAT   32
#define EFEAT   16
#define ENCD    64
#define HIDD    128
#define HEADS   4
#define HID4    512    // HEADS*HID
#define MAXS    10
#define TVAR    1536   // 3*HID4: [src-attn | tgt-attn | tgt-msg] node tables

typedef unsigned short ushort_t;

static __device__ __forceinline__ float bfbits2f(unsigned int hi16) {
    return __uint_as_float(hi16);
}
static __device__ __forceinline__ void load8bf(const ushort_t* p, float* f) {
    uint4 v = *reinterpret_cast<const uint4*>(p);
    f[0] = bfbits2f(v.x << 16); f[1] = bfbits2f(v.x & 0xffff0000u);
    f[2] = bfbits2f(v.y << 16); f[3] = bfbits2f(v.y & 0xffff0000u);
    f[4] = bfbits2f(v.z << 16); f[5] = bfbits2f(v.z & 0xffff0000u);
    f[6] = bfbits2f(v.w << 16); f[7] = bfbits2f(v.w & 0xffff0000u);
}
static __device__ __forceinline__ unsigned short f2bf(float x) {
    __hip_bfloat16 h = __float2bfloat16(x);
    return *reinterpret_cast<unsigned short*>(&h);
}

// ---------------- h0 = nf @ W_h ; h_cur = h0 ----------------
__global__ void k_h0(const float* __restrict__ nf, const float* __restrict__ Wh,
                     float* __restrict__ h0, float* __restrict__ hA) {
    int idx = blockIdx.x * blockDim.x + threadIdx.x;   // N*HID threads
    int n = idx >> 7, c = idx & 127;
    float s = 0.f;
#pragma unroll
    for (int k = 0; k < NFEAT; ++k) s += nf[n * NFEAT + k] * Wh[k * HIDD + c];
    h0[idx] = s; hA[idx] = s;
}

// ---------------- e_hid = ef @ W_e ----------------
__global__ void k_ehid(const float* __restrict__ ef, const float* __restrict__ We,
                       float* __restrict__ eh) {
    int idx = blockIdx.x * blockDim.x + threadIdx.x;   // E*HID threads
    int e = idx >> 7, c = idx & 127;
    float s = 0.f;
#pragma unroll
    for (int k = 0; k < EFEAT; ++k) s += ef[e * EFEAT + k] * We[k * HIDD + c];
    eh[idx] = s;
}

// ---------------- attn mask = any(ef != 0) ----------------
__global__ void k_mask(const float* __restrict__ ef, int* __restrict__ mask) {
    int e = blockIdx.x * blockDim.x + threadIdx.x;
    int m = 0;
#pragma unroll
    for (int k = 0; k < EFEAT; ++k) m |= (ef[e * EFEAT + k] != 0.f);
    mask[e] = m;
}

// ------- pack weights: Wvar/Wfix [128][1536], Weam [128][1024] -------
__global__ void k_pack(const float* __restrict__ Wa, const float* __restrict__ Wm,
                       float* __restrict__ Wvar, float* __restrict__ Wfix,
                       float* __restrict__ Weam) {
    int idx = blockIdx.x * blockDim.x + threadIdx.x;   // 128*1536 threads
    int k = idx / TVAR, c = idx % TVAR;
    float v, f;
    if (c < 512)       { v = Wa[k * HID4 + c];                 f = Wa[(128 + k) * HID4 + c]; }
    else if (c < 1024) { v = Wa[(384 + k) * HID4 + (c - 512)]; f = Wa[(512 + k) * HID4 + (c - 512)]; }
    else               { v = Wm[(128 + k) * HID4 + (c - 1024)]; f = Wm[(256 + k) * HID4 + (c - 1024)]; }
    Wvar[idx] = v; Wfix[idx] = f;
    if (c < 1024) {
        float wv = (c < 512) ? Wa[(256 + k) * HID4 + c] : Wm[k * HID4 + (c - 512)];
        Weam[k * 1024 + c] = wv;
    }
}

// ------------- generic C[M][NC] = A[M][128] @ W[128][NC] (+Cadd), store f32/bf16 -------------
// block 256 threads, 64x64 tile, K staged in 32-chunks
template <bool BF16, bool ADD>
__global__ __launch_bounds__(256) void k_gemm128(const float* __restrict__ A,
                                                 const float* __restrict__ W,
                                                 const float* __restrict__ Cadd,
                                                 void* __restrict__ C, int NC) {
    __shared__ float At[32][68];   // At[k][m]  (transposed A chunk)
    __shared__ float Wt[32][68];   // Wt[k][n]
    const int tid = threadIdx.x;
    const int m0 = blockIdx.y * 64, n0 = blockIdx.x * 64;
    const int tr = tid >> 4, tc = tid & 15;
    float acc[4][4] = {};

    for (int kc = 0; kc < 128; kc += 32) {
        {   // stage A chunk (transpose)
            int r = tid >> 2, kq = (tid & 3) << 3;
            const float4* pa = reinterpret_cast<const float4*>(A + (size_t)(m0 + r) * 128 + kc + kq);
            float4 a0 = pa[0], a1 = pa[1];
            At[kq + 0][r] = a0.x; At[kq + 1][r] = a0.y; At[kq + 2][r] = a0.z; At[kq + 3][r] = a0.w;
            At[kq + 4][r] = a1.x; At[kq + 5][r] = a1.y; At[kq + 6][r] = a1.z; At[kq + 7][r] = a1.w;
        }
        {   // stage W chunk
            int kk = tid >> 3, c8 = (tid & 7) << 3;
            const float4* pw = reinterpret_cast<const float4*>(W + (size_t)(kc + kk) * NC + n0 + c8);
            *reinterpret_cast<float4*>(&Wt[kk][c8])     = pw[0];
            *reinterpret_cast<float4*>(&Wt[kk][c8 + 4]) = pw[1];
        }
        __syncthreads();
#pragma unroll
        for (int kk = 0; kk < 32; ++kk) {
            float4 av = *reinterpret_cast<const float4*>(&At[kk][tr << 2]);
            float4 wv = *reinterpret_cast<const float4*>(&Wt[kk][tc << 2]);
            acc[0][0] += av.x * wv.x; acc[0][1] += av.x * wv.y; acc[0][2] += av.x * wv.z; acc[0][3] += av.x * wv.w;
            acc[1][0] += av.y * wv.x; acc[1][1] += av.y * wv.y; acc[1][2] += av.y * wv.z; acc[1][3] += av.y * wv.w;
            acc[2][0] += av.z * wv.x; acc[2][1] += av.z * wv.y; acc[2][2] += av.z * wv.z; acc[2][3] += av.z * wv.w;
            acc[3][0] += av.w * wv.x; acc[3][1] += av.w * wv.y; acc[3][2] += av.w * wv.z; acc[3][3] += av.w * wv.w;
        }
        __syncthreads();
    }
#pragma unroll
    for (int i = 0; i < 4; ++i) {
        int row = m0 + (tr << 2) + i;
        int col = n0 + (tc << 2);
        float o0 = acc[i][0], o1 = acc[i][1], o2 = acc[i][2], o3 = acc[i][3];
        if (ADD) {
            float4 ad = *reinterpret_cast<const float4*>(Cadd + (size_t)row * NC + col);
            o0 += ad.x; o1 += ad.y; o2 += ad.z; o3 += ad.w;
        }
        if (BF16) {
            ushort4 u; u.x = f2bf(o0); u.y = f2bf(o1); u.z = f2bf(o2); u.w = f2bf(o3);
            *reinterpret_cast<ushort4*>(reinterpret_cast<ushort_t*>(C) + (size_t)row * NC + col) = u;
        } else {
            float4 o; o.x = o0; o.y = o1; o.z = o2; o.w = o3;
            *reinterpret_cast<float4*>(reinterpret_cast<float*>(C) + (size_t)row * NC + col) = o;
        }
    }
}

// ---------------- CSR build ----------------
__global__ void k_zero(int* p) { p[blockIdx.x * blockDim.x + threadIdx.x] = 0; }
__global__ void k_count(const int* __restrict__ src, int* __restrict__ deg) {
    int e = blockIdx.x * blockDim.x + threadIdx.x;
    atomicAdd(&deg[src[e]], 1);
}
__global__ __launch_bounds__(1024) void k_scan(const int* __restrict__ deg,
                                               int* __restrict__ offs, int* __restrict__ cursor) {
    __shared__ int sm[1024];
    int t = threadIdx.x;
    int d0 = deg[t * 4], d1 = deg[t * 4 + 1], d2 = deg[t * 4 + 2], d3 = deg[t * 4 + 3];
    int s = d0 + d1 + d2 + d3;
    sm[t] = s; __syncthreads();
    for (int o = 1; o < 1024; o <<= 1) {
        int v = (t >= o) ? sm[t - o] : 0;
        __syncthreads();
        sm[t] += v;
        __syncthreads();
    }
    int run = sm[t] - s;
    offs[t * 4] = run;     cursor[t * 4] = run;     run += d0;
    offs[t * 4 + 1] = run; cursor[t * 4 + 1] = run; run += d1;
    offs[t * 4 + 2] = run; cursor[t * 4 + 2] = run; run += d2;
    offs[t * 4 + 3] = run; cursor[t * 4 + 3] = run;
    if (t == 1023) offs[4096] = run + d3;
}
__global__ void k_fill(const int* __restrict__ src, int* __restrict__ cursor, int* __restrict__ eids) {
    int e = blockIdx.x * blockDim.x + threadIdx.x;
    int pos = atomicAdd(&cursor[src[e]], 1);
    eids[pos] = e;
}

// ------ fused edge pass: logits -> online segment softmax -> aggregate -> tanh -> update ------
// one wave per node; lane owns 8 of 512 (head,channel) slots; head = lane>>4
__global__ __launch_bounds__(256) void k_edge(const ushort_t* __restrict__ T,    // [N][1536] bf16
                                              const ushort_t* __restrict__ eam,  // [E][1024] bf16
                                              const int* __restrict__ tgt,
                                              const int* __restrict__ offs,
                                              const int* __restrict__ eids,
                                              const int* __restrict__ mask,
                                              const float* __restrict__ a_kern,
                                              const int* __restrict__ n_states,
                                              const float* __restrict__ h_old,
                                              float* __restrict__ h_new, int iter) {
    const int n = (blockIdx.x << 2) + (threadIdx.x >> 6);
    const int lane = threadIdx.x & 63;
    const int c0 = lane << 3;
    const int e0 = offs[n], e1 = offs[n + 1];

    float ak[8];
    {
        const float4* p = reinterpret_cast<const float4*>(a_kern + ((lane & 15) << 3));
        float4 a0 = p[0], a1 = p[1];
        ak[0] = a0.x; ak[1] = a0.y; ak[2] = a0.z; ak[3] = a0.w;
        ak[4] = a1.x; ak[5] = a1.y; ak[6] = a1.z; ak[7] = a1.w;
    }
    float asrc[8];
    load8bf(T + (size_t)n * TVAR + c0, asrc);

    float m = -INFINITY, s = 0.f;
    float acc[8] = {0, 0, 0, 0, 0, 0, 0, 0};

    for (int q = e0; q < e1; ++q) {
        int e = eids[q];
        if (!mask[e]) continue;                    // masked edge: contributes nothing (unless dead)
        int t = tgt[e];
        float ea[8], tt[8], em[8], tm[8];
        load8bf(eam + (size_t)e * 1024 + c0, ea);
        load8bf(T + (size_t)t * TVAR + 512 + c0, tt);
        load8bf(eam + (size_t)e * 1024 + 512 + c0, em);
        load8bf(T + (size_t)t * TVAR + 1024 + c0, tm);
        float p = 0.f;
#pragma unroll
        for (int j = 0; j < 8; ++j) {
            float v = asrc[j] + ea[j] + tt[j];
            v = (v > 0.f) ? v : 0.2f * v;          // leaky_relu 0.2
            p = fmaf(v, ak[j], p);
        }
        p += __shfl_xor(p, 1);
        p += __shfl_xor(p, 2);
        p += __shfl_xor(p, 4);
        p += __shfl_xor(p, 8);                     // per-head logit (16-lane group)
        float mn = fmaxf(m, p);
        float wgt = __expf(p - mn);
        float sc = __expf(m - mn);                 // m=-inf first time -> 0
        s = s * sc + wgt;
#pragma unroll
        for (int j = 0; j < 8; ++j) acc[j] = acc[j] * sc + wgt * (em[j] + tm[j]);
        m = mn;
    }
    if (e1 > e0 && m == -INFINITY) {
        // dead node (all edges masked): ref gives uniform attention over ALL its edges
        s = (float)(e1 - e0);
        for (int q = e0; q < e1; ++q) {
            int e = eids[q]; int t = tgt[e];
            float em[8], tm[8];
            load8bf(eam + (size_t)e * 1024 + 512 + c0, em);
            load8bf(T + (size_t)t * TVAR + 1024 + c0, tm);
#pragma unroll
            for (int j = 0; j < 8; ++j) acc[j] += em[j] + tm[j];
        }
    }
    float inv = (e1 > e0) ? (1.f / s) : 0.f;
    float r[8];
#pragma unroll
    for (int j = 0; j < 8; ++j) {
        float v = acc[j] * inv;
        v += __shfl_xor(v, 16);
        v += __shfl_xor(v, 32);                    // sum 4 heads (same channel)
        r[j] = v;
    }
    bool upd = iter < n_states[n];
    if (lane < 16) {
        float out[8];
#pragma unroll
        for (int j = 0; j < 8; ++j)
            out[j] = upd ? tanhf(r[j]) : h_old[(size_t)n * HIDD + c0 + j];
        float4* ph = reinterpret_cast<float4*>(h_new + (size_t)n * HIDD + c0);
        float4 o0, o1;
        o0.x = out[0]; o0.y = out[1]; o0.z = out[2]; o0.w = out[3];
        o1.x = out[4]; o1.y = out[5]; o1.z = out[6]; o1.w = out[7];
        ph[0] = o0; ph[1] = o1;
    }
}

// ---------------- out = h[cs] @ W_g ----------------
__global__ void k_out(const float* __restrict__ h, const int* __restrict__ cs,
                      const float* __restrict__ Wg, float* __restrict__ out) {
    int idx = blockIdx.x * blockDim.x + threadIdx.x;   // B*ENC threads
    int b = idx >> 6, c = idx & 63;
    int n = cs[b];
    float s = 0.f;
#pragma unroll
    for (int k = 0; k < HIDD; ++k) s += h[(size_t)n * HIDD + k] * Wg[k * ENCD + c];
    out[idx] = s;
}

extern "C" void kernel_launch(void* const* d_in, const int* in_sizes, int n_in,
                              void* d_out, int out_size, void* d_ws, size_t ws_size,
                              hipStream_t stream) {
    const float* nf  = (const float*)d_in[0];
    const float* ef  = (const float*)d_in[1];
    const int* eidx  = (const int*)d_in[2];
    const int* cs    = (const int*)d_in[3];
    const int* nst   = (const int*)d_in[4];
    const float* Wh  = (const float*)d_in[5];
    const float* We  = (const float*)d_in[6];
    const float* Wa  = (const float*)d_in[7];
    const float* Wm  = (const float*)d_in[8];
    const float* akn = (const float*)d_in[9];
    const float* Wg  = (const float*)d_in[10];
    const int* src = eidx;
    const int* tgt = eidx + N_EDGES;

    char* w = (char*)d_ws;
    size_t off = 0;
    auto alloc = [&](size_t bytes) -> void* {
        void* p = w + off;
        off = (off + bytes + 255) & ~(size_t)255;
        return p;
    };
    float* h0      = (float*)alloc((size_t)N_NODES * HIDD * 4);
    float* hA      = (float*)alloc((size_t)N_NODES * HIDD * 4);
    float* hB      = (float*)alloc((size_t)N_NODES * HIDD * 4);
    float* eh      = (float*)alloc((size_t)N_EDGES * HIDD * 4);
    int* mask      = (int*)alloc((size_t)N_EDGES * 4);
    ushort_t* eam  = (ushort_t*)alloc((size_t)N_EDGES * 1024 * 2);
    float* Tfix    = (float*)alloc((size_t)N_NODES * TVAR * 4);
    ushort_t* Tcur = (ushort_t*)alloc((size_t)N_NODES * TVAR * 2);
    float* Wvar    = (float*)alloc((size_t)128 * TVAR * 4);
    float* Wfix    = (float*)alloc((size_t)128 * TVAR * 4);
    float* Weam    = (float*)alloc((size_t)128 * 1024 * 4);
    int* deg       = (int*)alloc((size_t)N_NODES * 4);
    int* offs      = (int*)alloc((size_t)(N_NODES + 1) * 4);
    int* cursor    = (int*)alloc((size_t)N_NODES * 4);
    int* eids      = (int*)alloc((size_t)N_EDGES * 4);
    (void)ws_size; (void)in_sizes; (void)n_in; (void)out_size;  // ~133 MB total used

    k_pack<<<(128 * TVAR) / 256, 256, 0, stream>>>(Wa, Wm, Wvar, Wfix, Weam);
    k_h0<<<(N_NODES * HIDD) / 256, 256, 0, stream>>>(nf, Wh, h0, hA);
    k_ehid<<<(N_EDGES * HIDD) / 256, 256, 0, stream>>>(ef, We, eh);
    k_mask<<<N_EDGES / 256, 256, 0, stream>>>(ef, mask);

    dim3 g_eam(1024 / 64, N_EDGES / 64);
    k_gemm128<true, false><<<g_eam, 256, 0, stream>>>(eh, Weam, nullptr, eam, 1024);
    dim3 g_tab(TVAR / 64, N_NODES / 64);
    k_gemm128<false, false><<<g_tab, 256, 0, stream>>>(h0, Wfix, nullptr, Tfix, TVAR);

    k_zero<<<N_NODES / 256, 256, 0, stream>>>(deg);
    k_count<<<N_EDGES / 256, 256, 0, stream>>>(src, deg);
    k_scan<<<1, 1024, 0, stream>>>(deg, offs, cursor);
    k_fill<<<N_EDGES / 256, 256, 0, stream>>>(src, cursor, eids);

    float* hcur = hA; float* hnext = hB;
    for (int i = 0; i < MAXS; ++i) {
        k_gemm128<true, true><<<g_tab, 256, 0, stream>>>(hcur, Wvar, Tfix, Tcur, TVAR);
        k_edge<<<N_NODES / 4, 256, 0, stream>>>(Tcur, eam, tgt, offs, eids, mask, akn, nst,
                                                hcur, hnext, i);
        float* tmp = hcur; hcur = hnext; hnext = tmp;
    }
    k_out<<<(BATCH * ENCD) / 256, 256, 0, stream>>>(hcur, cs, Wg, (float*)d_out);
}

// Round 4
// 723.795 us; speedup vs baseline: 1.1121x; 1.1121x over previous
//
#include <hip/hip_runtime.h>
#include <hip/hip_bf16.h>

// Problem constants (fixed by the reference)
#define N_NODES 4096
#define N_EDGES 32768
#define BATCH   1024
#define NFEAT   32
#define EFEAT   16
#define ENCD    64
#define HIDD    128
#define HEADS   4
#define HID4    512    // HEADS*HID
#define MAXS    10
#define TVAR    1536   // 3*HID4: [src-attn | tgt-attn | tgt-msg] node tables

typedef unsigned short ushort_t;
typedef __bf16 bf16x8 __attribute__((ext_vector_type(8)));
typedef float f32x4 __attribute__((ext_vector_type(4)));

static __device__ __forceinline__ float bfbits2f(unsigned int hi16) {
    return __uint_as_float(hi16);
}
static __device__ __forceinline__ void load8bf(const ushort_t* p, float* f) {
    uint4 v = *reinterpret_cast<const uint4*>(p);
    f[0] = bfbits2f(v.x << 16); f[1] = bfbits2f(v.x & 0xffff0000u);
    f[2] = bfbits2f(v.y << 16); f[3] = bfbits2f(v.y & 0xffff0000u);
    f[4] = bfbits2f(v.z << 16); f[5] = bfbits2f(v.z & 0xffff0000u);
    f[6] = bfbits2f(v.w << 16); f[7] = bfbits2f(v.w & 0xffff0000u);
}
static __device__ __forceinline__ unsigned short f2bf(float x) {
    __hip_bfloat16 h = __float2bfloat16(x);
    return *reinterpret_cast<unsigned short*>(&h);
}

// ---------------- h0 = nf @ W_h ; h_cur = h0 (f32 + bf16 mirrors) ----------------
__global__ void k_h0(const float* __restrict__ nf, const float* __restrict__ Wh,
                     ushort_t* __restrict__ h0bf, float* __restrict__ hA,
                     ushort_t* __restrict__ hAbf) {
    int idx = blockIdx.x * blockDim.x + threadIdx.x;   // N*HID threads
    int n = idx >> 7, c = idx & 127;
    float s = 0.f;
#pragma unroll
    for (int k = 0; k < NFEAT; ++k) s += nf[n * NFEAT + k] * Wh[k * HIDD + c];
    ushort_t b = f2bf(s);
    h0bf[idx] = b; hA[idx] = s; hAbf[idx] = b;
}

// ---------------- e_hid = ef @ W_e (bf16) ----------------
__global__ void k_ehid(const float* __restrict__ ef, const float* __restrict__ We,
                       ushort_t* __restrict__ eh) {
    int idx = blockIdx.x * blockDim.x + threadIdx.x;   // E*HID threads
    int e = idx >> 7, c = idx & 127;
    float s = 0.f;
#pragma unroll
    for (int k = 0; k < EFEAT; ++k) s += ef[e * EFEAT + k] * We[k * HIDD + c];
    eh[idx] = f2bf(s);
}

// ---------------- attn mask = any(ef != 0) ----------------
__global__ void k_mask(const float* __restrict__ ef, int* __restrict__ mask) {
    int e = blockIdx.x * blockDim.x + threadIdx.x;
    int m = 0;
#pragma unroll
    for (int k = 0; k < EFEAT; ++k) m |= (ef[e * EFEAT + k] != 0.f);
    mask[e] = m;
}

// ------- pack weights TRANSPOSED bf16: WvarT/WfixT [1536][128], WeamT [1024][128] -------
__global__ void k_pack(const float* __restrict__ Wa, const float* __restrict__ Wm,
                       ushort_t* __restrict__ WvarT, ushort_t* __restrict__ WfixT,
                       ushort_t* __restrict__ WeamT) {
    int idx = blockIdx.x * blockDim.x + threadIdx.x;   // 128*1536 threads
    int k = idx / TVAR, c = idx % TVAR;
    float v, f;
    if (c < 512)       { v = Wa[k * HID4 + c];                 f = Wa[(128 + k) * HID4 + c]; }
    else if (c < 1024) { v = Wa[(384 + k) * HID4 + (c - 512)]; f = Wa[(512 + k) * HID4 + (c - 512)]; }
    else               { v = Wm[(128 + k) * HID4 + (c - 1024)]; f = Wm[(256 + k) * HID4 + (c - 1024)]; }
    WvarT[c * 128 + k] = f2bf(v);
    WfixT[c * 128 + k] = f2bf(f);
    if (c < 1024) {
        float wv = (c < 512) ? Wa[(256 + k) * HID4 + c] : Wm[k * HID4 + (c - 512)];
        WeamT[c * 128 + k] = f2bf(wv);
    }
}

// ------------- MFMA GEMM: C[M][NC] = bf16( A[M][128] @ BT[NC][128]^T (+Cadd) ) -------------
// block 256 = 4 waves; block tile 64 rows x 64 cols; wave = 16 rows x 64 cols.
// mfma_f32_16x16x32_bf16 layouts (m89/m91): A row=l&15,k=(l>>4)*8+j; B col=l&15; D col=l&15,row=(l>>4)*4+r
template <bool ADD>
__global__ __launch_bounds__(256) void k_mgemm(const ushort_t* __restrict__ A,
                                               const ushort_t* __restrict__ BT,
                                               const ushort_t* __restrict__ Cadd,
                                               ushort_t* __restrict__ C, int NC) {
    const int tid = threadIdx.x;
    const int l = tid & 63;
    const int m0 = blockIdx.y * 64 + ((tid >> 6) << 4);
    const int n0 = blockIdx.x * 64;
    const int lr = l & 15;
    const int kg = (l >> 4) << 3;

    const ushort_t* pa = A + (size_t)(m0 + lr) * 128 + kg;
    bf16x8 a0 = *(const bf16x8*)(pa);
    bf16x8 a1 = *(const bf16x8*)(pa + 32);
    bf16x8 a2 = *(const bf16x8*)(pa + 64);
    bf16x8 a3 = *(const bf16x8*)(pa + 96);

    f32x4 acc[4];
#pragma unroll
    for (int ct = 0; ct < 4; ++ct) {
        const ushort_t* pb = BT + (size_t)(n0 + ct * 16 + lr) * 128 + kg;
        f32x4 c = {0.f, 0.f, 0.f, 0.f};
        c = __builtin_amdgcn_mfma_f32_16x16x32_bf16(a0, *(const bf16x8*)(pb),      c, 0, 0, 0);
        c = __builtin_amdgcn_mfma_f32_16x16x32_bf16(a1, *(const bf16x8*)(pb + 32), c, 0, 0, 0);
        c = __builtin_amdgcn_mfma_f32_16x16x32_bf16(a2, *(const bf16x8*)(pb + 64), c, 0, 0, 0);
        c = __builtin_amdgcn_mfma_f32_16x16x32_bf16(a3, *(const bf16x8*)(pb + 96), c, 0, 0, 0);
        acc[ct] = c;
    }
    const int rbase = (l >> 4) << 2;
#pragma unroll
    for (int ct = 0; ct < 4; ++ct) {
        int col = n0 + ct * 16 + lr;
#pragma unroll
        for (int r = 0; r < 4; ++r) {
            size_t idx = (size_t)(m0 + rbase + r) * NC + col;
            float v = acc[ct][r];
            if (ADD) v += bfbits2f(((unsigned)Cadd[idx]) << 16);
            C[idx] = f2bf(v);
        }
    }
}

// ---------------- CSR build ----------------
__global__ void k_zero(int* p) { p[blockIdx.x * blockDim.x + threadIdx.x] = 0; }
__global__ void k_count(const int* __restrict__ src, int* __restrict__ deg) {
    int e = blockIdx.x * blockDim.x + threadIdx.x;
    atomicAdd(&deg[src[e]], 1);
}
__global__ __launch_bounds__(1024) void k_scan(const int* __restrict__ deg,
                                               int* __restrict__ offs, int* __restrict__ cursor) {
    __shared__ int sm[1024];
    int t = threadIdx.x;
    int d0 = deg[t * 4], d1 = deg[t * 4 + 1], d2 = deg[t * 4 + 2], d3 = deg[t * 4 + 3];
    int s = d0 + d1 + d2 + d3;
    sm[t] = s; __syncthreads();
    for (int o = 1; o < 1024; o <<= 1) {
        int v = (t >= o) ? sm[t - o] : 0;
        __syncthreads();
        sm[t] += v;
        __syncthreads();
    }
    int run = sm[t] - s;
    offs[t * 4] = run;     cursor[t * 4] = run;     run += d0;
    offs[t * 4 + 1] = run; cursor[t * 4 + 1] = run; run += d1;
    offs[t * 4 + 2] = run; cursor[t * 4 + 2] = run; run += d2;
    offs[t * 4 + 3] = run; cursor[t * 4 + 3] = run;
    if (t == 1023) offs[4096] = run + d3;
}
__global__ void k_fill(const int* __restrict__ src, int* __restrict__ cursor, int* __restrict__ eids) {
    int e = blockIdx.x * blockDim.x + threadIdx.x;
    int pos = atomicAdd(&cursor[src[e]], 1);
    eids[pos] = e;
}

// ------ fused edge pass: logits -> online segment softmax -> aggregate -> tanh -> update ------
// one wave per node; lane owns 8 of 512 (head,channel) slots; head = lane>>4
__global__ __launch_bounds__(256) void k_edge(const ushort_t* __restrict__ T,    // [N][1536] bf16
                                              const ushort_t* __restrict__ eam,  // [E][1024] bf16
                                              const int* __restrict__ tgt,
                                              const int* __restrict__ offs,
                                              const int* __restrict__ eids,
                                              const int* __restrict__ mask,
                                              const float* __restrict__ a_kern,
                                              const int* __restrict__ n_states,
                                              const float* __restrict__ h_old,
                                              float* __restrict__ h_new,
                                              ushort_t* __restrict__ h_new_bf, int iter) {
    const int n = (blockIdx.x << 2) + (threadIdx.x >> 6);
    const int lane = threadIdx.x & 63;
    const int c0 = lane << 3;
    const int e0 = offs[n], e1 = offs[n + 1];

    float ak[8];
    {
        const float4* p = reinterpret_cast<const float4*>(a_kern + ((lane & 15) << 3));
        float4 a0 = p[0], a1 = p[1];
        ak[0] = a0.x; ak[1] = a0.y; ak[2] = a0.z; ak[3] = a0.w;
        ak[4] = a1.x; ak[5] = a1.y; ak[6] = a1.z; ak[7] = a1.w;
    }
    float asrc[8];
    load8bf(T + (size_t)n * TVAR + c0, asrc);

    float m = -INFINITY, s = 0.f;
    float acc[8] = {0, 0, 0, 0, 0, 0, 0, 0};

    for (int q = e0; q < e1; ++q) {
        int e = eids[q];
        if (!mask[e]) continue;                    // masked edge: contributes nothing (unless dead)
        int t = tgt[e];
        float ea[8], tt[8], em[8], tm[8];
        load8bf(eam + (size_t)e * 1024 + c0, ea);
        load8bf(T + (size_t)t * TVAR + 512 + c0, tt);
        load8bf(eam + (size_t)e * 1024 + 512 + c0, em);
        load8bf(T + (size_t)t * TVAR + 1024 + c0, tm);
        float p = 0.f;
#pragma unroll
        for (int j = 0; j < 8; ++j) {
            float v = asrc[j] + ea[j] + tt[j];
            v = (v > 0.f) ? v : 0.2f * v;          // leaky_relu 0.2
            p = fmaf(v, ak[j], p);
        }
        p += __shfl_xor(p, 1);
        p += __shfl_xor(p, 2);
        p += __shfl_xor(p, 4);
        p += __shfl_xor(p, 8);                     // per-head logit (16-lane group)
        float mn = fmaxf(m, p);
        float wgt = __expf(p - mn);
        float sc = __expf(m - mn);                 // m=-inf first time -> 0
        s = s * sc + wgt;
#pragma unroll
        for (int j = 0; j < 8; ++j) acc[j] = acc[j] * sc + wgt * (em[j] + tm[j]);
        m = mn;
    }
    if (e1 > e0 && m == -INFINITY) {
        // dead node (all edges masked): ref gives uniform attention over ALL its edges
        s = (float)(e1 - e0);
        for (int q = e0; q < e1; ++q) {
            int e = eids[q]; int t = tgt[e];
            float em[8], tm[8];
            load8bf(eam + (size_t)e * 1024 + 512 + c0, em);
            load8bf(T + (size_t)t * TVAR + 1024 + c0, tm);
#pragma unroll
            for (int j = 0; j < 8; ++j) acc[j] += em[j] + tm[j];
        }
    }
    float inv = (e1 > e0) ? (1.f / s) : 0.f;
    float r[8];
#pragma unroll
    for (int j = 0; j < 8; ++j) {
        float v = acc[j] * inv;
        v += __shfl_xor(v, 16);
        v += __shfl_xor(v, 32);                    // sum 4 heads (same channel)
        r[j] = v;
    }
    bool upd = iter < n_states[n];
    if (lane < 16) {
        float out[8];
#pragma unroll
        for (int j = 0; j < 8; ++j)
            out[j] = upd ? tanhf(r[j]) : h_old[(size_t)n * HIDD + c0 + j];
        float4* ph = reinterpret_cast<float4*>(h_new + (size_t)n * HIDD + c0);
        float4 o0, o1;
        o0.x = out[0]; o0.y = out[1]; o0.z = out[2]; o0.w = out[3];
        o1.x = out[4]; o1.y = out[5]; o1.z = out[6]; o1.w = out[7];
        ph[0] = o0; ph[1] = o1;
        ushort4 b0, b1;
        b0.x = f2bf(out[0]); b0.y = f2bf(out[1]); b0.z = f2bf(out[2]); b0.w = f2bf(out[3]);
        b1.x = f2bf(out[4]); b1.y = f2bf(out[5]); b1.z = f2bf(out[6]); b1.w = f2bf(out[7]);
        ushort4* pb = reinterpret_cast<ushort4*>(h_new_bf + (size_t)n * HIDD + c0);
        pb[0] = b0; pb[1] = b1;
    }
}

// ---------------- out = h[cs] @ W_g ----------------
__global__ void k_out(const float* __restrict__ h, const int* __restrict__ cs,
                      const float* __restrict__ Wg, float* __restrict__ out) {
    int idx = blockIdx.x * blockDim.x + threadIdx.x;   // B*ENC threads
    int b = idx >> 6, c = idx & 63;
    int n = cs[b];
    float s = 0.f;
#pragma unroll
    for (int k = 0; k < HIDD; ++k) s += h[(size_t)n * HIDD + k] * Wg[k * ENCD + c];
    out[idx] = s;
}

extern "C" void kernel_launch(void* const* d_in, const int* in_sizes, int n_in,
                              void* d_out, int out_size, void* d_ws, size_t ws_size,
                              hipStream_t stream) {
    const float* nf  = (const float*)d_in[0];
    const float* ef  = (const float*)d_in[1];
    const int* eidx  = (const int*)d_in[2];
    const int* cs    = (const int*)d_in[3];
    const int* nst   = (const int*)d_in[4];
    const float* Wh  = (const float*)d_in[5];
    const float* We  = (const float*)d_in[6];
    const float* Wa  = (const float*)d_in[7];
    const float* Wm  = (const float*)d_in[8];
    const float* akn = (const float*)d_in[9];
    const float* Wg  = (const float*)d_in[10];
    const int* src = eidx;
    const int* tgt = eidx + N_EDGES;

    char* w = (char*)d_ws;
    size_t off = 0;
    auto alloc = [&](size_t bytes) -> void* {
        void* p = w + off;
        off = (off + bytes + 255) & ~(size_t)255;
        return p;
    };
    float* hA       = (float*)alloc((size_t)N_NODES * HIDD * 4);
    float* hB       = (float*)alloc((size_t)N_NODES * HIDD * 4);
    ushort_t* hAbf  = (ushort_t*)alloc((size_t)N_NODES * HIDD * 2);
    ushort_t* hBbf  = (ushort_t*)alloc((size_t)N_NODES * HIDD * 2);
    ushort_t* h0bf  = (ushort_t*)alloc((size_t)N_NODES * HIDD * 2);
    ushort_t* eh    = (ushort_t*)alloc((size_t)N_EDGES * HIDD * 2);
    int* mask       = (int*)alloc((size_t)N_EDGES * 4);
    ushort_t* eam   = (ushort_t*)alloc((size_t)N_EDGES * 1024 * 2);
    ushort_t* Tfix  = (ushort_t*)alloc((size_t)N_NODES * TVAR * 2);
    ushort_t* Tcur  = (ushort_t*)alloc((size_t)N_NODES * TVAR * 2);
    ushort_t* WvarT = (ushort_t*)alloc((size_t)TVAR * 128 * 2);
    ushort_t* WfixT = (ushort_t*)alloc((size_t)TVAR * 128 * 2);
    ushort_t* WeamT = (ushort_t*)alloc((size_t)1024 * 128 * 2);
    int* deg        = (int*)alloc((size_t)N_NODES * 4);
    int* offs       = (int*)alloc((size_t)(N_NODES + 1) * 4);
    int* cursor     = (int*)alloc((size_t)N_NODES * 4);
    int* eids       = (int*)alloc((size_t)N_EDGES * 4);
    (void)ws_size; (void)in_sizes; (void)n_in; (void)out_size;  // ~110 MB used

    k_pack<<<(128 * TVAR) / 256, 256, 0, stream>>>(Wa, Wm, WvarT, WfixT, WeamT);
    k_h0<<<(N_NODES * HIDD) / 256, 256, 0, stream>>>(nf, Wh, h0bf, hA, hAbf);
    k_ehid<<<(N_EDGES * HIDD) / 256, 256, 0, stream>>>(ef, We, eh);
    k_mask<<<N_EDGES / 256, 256, 0, stream>>>(ef, mask);

    dim3 g_eam(1024 / 64, N_EDGES / 64);
    k_mgemm<false><<<g_eam, 256, 0, stream>>>(eh, WeamT, nullptr, eam, 1024);
    dim3 g_tab(TVAR / 64, N_NODES / 64);
    k_mgemm<false><<<g_tab, 256, 0, stream>>>(h0bf, WfixT, nullptr, Tfix, TVAR);

    k_zero<<<N_NODES / 256, 256, 0, stream>>>(deg);
    k_count<<<N_EDGES / 256, 256, 0, stream>>>(src, deg);
    k_scan<<<1, 1024, 0, stream>>>(deg, offs, cursor);
    k_fill<<<N_EDGES / 256, 256, 0, stream>>>(src, cursor, eids);

    float* hcur = hA; float* hnext = hB;
    ushort_t* hcbf = hAbf; ushort_t* hnbf = hBbf;
    for (int i = 0; i < MAXS; ++i) {
        k_mgemm<true><<<g_tab, 256, 0, stream>>>(hcbf, WvarT, Tfix, Tcur, TVAR);
        k_edge<<<N_NODES / 4, 256, 0, stream>>>(Tcur, eam, tgt, offs, eids, mask, akn, nst,
                                                hcur, hnext, hnbf, i);
        float* tmp = hcur; hcur = hnext; hnext = tmp;
        ushort_t* tb = hcbf; hcbf = hnbf; hnbf = tb;
    }
    k_out<<<(BATCH * ENCD) / 256, 256, 0, stream>>>(hcur, cs, Wg, (float*)d_out);
}

// Round 6
// 667.678 us; speedup vs baseline: 1.2055x; 1.0840x over previous
//
#include <hip/hip_runtime.h>
#include <hip/hip_bf16.h>

// Problem constants (fixed by the reference)
#define N_NODES 4096
#define N_EDGES 32768
#define BATCH   1024
#define NFEAT   32
#define EFEAT   16
#define ENCD    64
#define HIDD    128
#define HEADS   4
#define HID4    512    // HEADS*HID
#define MAXS    10
#define TVAR    1536   // 3*HID4: [src-attn | tgt-attn | tgt-msg] node tables

typedef unsigned short ushort_t;
typedef __bf16 bf16x8 __attribute__((ext_vector_type(8)));
typedef float f32x4 __attribute__((ext_vector_type(4)));

static __device__ __forceinline__ float bfbits2f(unsigned int hi16) {
    return __uint_as_float(hi16);
}
static __device__ __forceinline__ void unpack8(uint4 v, float* f) {
    f[0] = bfbits2f(v.x << 16); f[1] = bfbits2f(v.x & 0xffff0000u);
    f[2] = bfbits2f(v.y << 16); f[3] = bfbits2f(v.y & 0xffff0000u);
    f[4] = bfbits2f(v.z << 16); f[5] = bfbits2f(v.z & 0xffff0000u);
    f[6] = bfbits2f(v.w << 16); f[7] = bfbits2f(v.w & 0xffff0000u);
}
static __device__ __forceinline__ void load8bf(const ushort_t* p, float* f) {
    unpack8(*reinterpret_cast<const uint4*>(p), f);
}
static __device__ __forceinline__ unsigned short f2bf(float x) {
    __hip_bfloat16 h = __float2bfloat16(x);
    return *reinterpret_cast<unsigned short*>(&h);
}
// packed bf16 pair add: s,a are 2xbf16 words; returns bf16(bf16_lo(s)+bf16_lo(a)) etc.
static __device__ __forceinline__ unsigned addpack(unsigned s, unsigned a) {
    float s0 = bfbits2f(s << 16), s1 = bfbits2f(s & 0xffff0000u);
    float a0 = bfbits2f(a << 16), a1 = bfbits2f(a & 0xffff0000u);
    unsigned r0 = f2bf(s0 + a0), r1 = f2bf(s1 + a1);
    return r0 | (r1 << 16);
}

// ---------------- h0 = nf @ W_h ; h_cur = h0 (f32 + bf16 mirrors) ----------------
__global__ void k_h0(const float* __restrict__ nf, const float* __restrict__ Wh,
                     ushort_t* __restrict__ h0bf, float* __restrict__ hA,
                     ushort_t* __restrict__ hAbf) {
    int idx = blockIdx.x * blockDim.x + threadIdx.x;   // N*HID threads
    int n = idx >> 7, c = idx & 127;
    float s = 0.f;
#pragma unroll
    for (int k = 0; k < NFEAT; ++k) s += nf[n * NFEAT + k] * Wh[k * HIDD + c];
    ushort_t b = f2bf(s);
    h0bf[idx] = b; hA[idx] = s; hAbf[idx] = b;
}

// ---------------- e_hid = ef @ W_e (bf16) ----------------
__global__ void k_ehid(const float* __restrict__ ef, const float* __restrict__ We,
                       ushort_t* __restrict__ eh) {
    int idx = blockIdx.x * blockDim.x + threadIdx.x;   // E*HID threads
    int e = idx >> 7, c = idx & 127;
    float s = 0.f;
#pragma unroll
    for (int k = 0; k < EFEAT; ++k) s += ef[e * EFEAT + k] * We[k * HIDD + c];
    eh[idx] = f2bf(s);
}

// ---------------- attn mask = any(ef != 0) ----------------
__global__ void k_mask(const float* __restrict__ ef, int* __restrict__ mask) {
    int e = blockIdx.x * blockDim.x + threadIdx.x;
    int m = 0;
#pragma unroll
    for (int k = 0; k < EFEAT; ++k) m |= (ef[e * EFEAT + k] != 0.f);
    mask[e] = m;
}

// ------- pack weights TRANSPOSED bf16: WvarT/WfixT [1536][128], WeamT [1024][128] -------
__global__ void k_pack(const float* __restrict__ Wa, const float* __restrict__ Wm,
                       ushort_t* __restrict__ WvarT, ushort_t* __restrict__ WfixT,
                       ushort_t* __restrict__ WeamT) {
    int idx = blockIdx.x * blockDim.x + threadIdx.x;   // 128*1536 threads
    int k = idx / TVAR, c = idx % TVAR;
    float v, f;
    if (c < 512)       { v = Wa[k * HID4 + c];                 f = Wa[(128 + k) * HID4 + c]; }
    else if (c < 1024) { v = Wa[(384 + k) * HID4 + (c - 512)]; f = Wa[(512 + k) * HID4 + (c - 512)]; }
    else               { v = Wm[(128 + k) * HID4 + (c - 1024)]; f = Wm[(256 + k) * HID4 + (c - 1024)]; }
    WvarT[c * 128 + k] = f2bf(v);
    WfixT[c * 128 + k] = f2bf(f);
    if (c < 1024) {
        float wv = (c < 512) ? Wa[(256 + k) * HID4 + c] : Wm[k * HID4 + (c - 512)];
        WeamT[c * 128 + k] = f2bf(wv);
    }
}

// ------------- MFMA GEMM: C[M][NC] = bf16( A[M][128] @ BT[NC][128]^T (+Cadd) ) -------------
// block 256 = 4 waves; block tile 64 rows x 64 cols; wave = 16 rows x 64 cols.
// Epilogue: D fragments -> per-wave LDS tile -> coalesced dwordx4 stores (+ coalesced Cadd add).
template <bool ADD>
__global__ __launch_bounds__(256) void k_mgemm(const ushort_t* __restrict__ A,
                                               const ushort_t* __restrict__ BT,
                                               const ushort_t* __restrict__ Cadd,
                                               ushort_t* __restrict__ C, int NC) {
    __shared__ ushort_t lds[4][16][64];   // 8 KB: per-wave 16x64 bf16 staging
    const int tid = threadIdx.x;
    const int l = tid & 63;
    const int w = tid >> 6;
    const int m0 = blockIdx.y * 64 + (w << 4);
    const int n0 = blockIdx.x * 64;
    const int lr = l & 15;
    const int kg = (l >> 4) << 3;

    const ushort_t* pa = A + (size_t)(m0 + lr) * 128 + kg;
    bf16x8 a0 = *(const bf16x8*)(pa);
    bf16x8 a1 = *(const bf16x8*)(pa + 32);
    bf16x8 a2 = *(const bf16x8*)(pa + 64);
    bf16x8 a3 = *(const bf16x8*)(pa + 96);

    const int rbase = (l >> 4) << 2;
#pragma unroll
    for (int ct = 0; ct < 4; ++ct) {
        const ushort_t* pb = BT + (size_t)(n0 + ct * 16 + lr) * 128 + kg;
        f32x4 c = {0.f, 0.f, 0.f, 0.f};
        c = __builtin_amdgcn_mfma_f32_16x16x32_bf16(a0, *(const bf16x8*)(pb),      c, 0, 0, 0);
        c = __builtin_amdgcn_mfma_f32_16x16x32_bf16(a1, *(const bf16x8*)(pb + 32), c, 0, 0, 0);
        c = __builtin_amdgcn_mfma_f32_16x16x32_bf16(a2, *(const bf16x8*)(pb + 64), c, 0, 0, 0);
        c = __builtin_amdgcn_mfma_f32_16x16x32_bf16(a3, *(const bf16x8*)(pb + 96), c, 0, 0, 0);
#pragma unroll
        for (int r = 0; r < 4; ++r)
            lds[w][rbase + r][ct * 16 + lr] = f2bf(c[r]);
    }
    __syncthreads();
    // coalesced out: wave tile 16x64 ushort = 2 KB; per lane 2 x 16B chunks
#pragma unroll
    for (int i = 0; i < 2; ++i) {
        int ch = (i << 6) + l;              // chunk of 8 ushorts
        int row = ch >> 3, co = (ch & 7) << 3;
        uint4 sv = *(const uint4*)(&lds[w][row][co]);
        size_t gidx = (size_t)(m0 + row) * NC + n0 + co;
        if (ADD) {
            uint4 av = *(const uint4*)(Cadd + gidx);
            sv.x = addpack(sv.x, av.x);
            sv.y = addpack(sv.y, av.y);
            sv.z = addpack(sv.z, av.z);
            sv.w = addpack(sv.w, av.w);
        }
        *(uint4*)(C + gidx) = sv;
    }
}

// ---------------- CSR build ----------------
__global__ void k_zero(int* p) { p[blockIdx.x * blockDim.x + threadIdx.x] = 0; }
__global__ void k_count(const int* __restrict__ src, int* __restrict__ deg) {
    int e = blockIdx.x * blockDim.x + threadIdx.x;
    atomicAdd(&deg[src[e]], 1);
}
__global__ __launch_bounds__(1024) void k_scan(const int* __restrict__ deg,
                                               int* __restrict__ offs, int* __restrict__ cursor) {
    __shared__ int sm[1024];
    int t = threadIdx.x;
    int d0 = deg[t * 4], d1 = deg[t * 4 + 1], d2 = deg[t * 4 + 2], d3 = deg[t * 4 + 3];
    int s = d0 + d1 + d2 + d3;
    sm[t] = s; __syncthreads();
    for (int o = 1; o < 1024; o <<= 1) {
        int v = (t >= o) ? sm[t - o] : 0;
        __syncthreads();
        sm[t] += v;
        __syncthreads();
    }
    int run = sm[t] - s;
    offs[t * 4] = run;     cursor[t * 4] = run;     run += d0;
    offs[t * 4 + 1] = run; cursor[t * 4 + 1] = run; run += d1;
    offs[t * 4 + 2] = run; cursor[t * 4 + 2] = run; run += d2;
    offs[t * 4 + 3] = run; cursor[t * 4 + 3] = run;
    if (t == 1023) offs[4096] = run + d3;
}
__global__ void k_fill(const int* __restrict__ src, int* __restrict__ cursor, int* __restrict__ eids) {
    int e = blockIdx.x * blockDim.x + threadIdx.x;
    int pos = atomicAdd(&cursor[src[e]], 1);
    eids[pos] = e;
}

// ------ fused edge pass: logits -> online segment softmax -> aggregate -> tanh -> update ------
// one wave per node; lane owns 8 of 512 (head,channel) slots; head = lane>>4
// depth-1 software pipeline: prefetch next edge's indices + 4x16B while computing current
__global__ __launch_bounds__(256) void k_edge(const ushort_t* __restrict__ T,    // [N][1536] bf16
                                              const ushort_t* __restrict__ eam,  // [E][1024] bf16
                                              const int* __restrict__ tgt,
                                              const int* __restrict__ offs,
                                              const int* __restrict__ eids,
                                              const int* __restrict__ mask,
                                              const float* __restrict__ a_kern,
                                              const int* __restrict__ n_states,
                                              const float* __restrict__ h_old,
                                              float* __restrict__ h_new,
                                              ushort_t* __restrict__ h_new_bf, int iter) {
    const int n = (blockIdx.x << 2) + (threadIdx.x >> 6);
    const int lane = threadIdx.x & 63;
    const int c0 = lane << 3;
    const int e0 = offs[n], e1 = offs[n + 1];

    float ak[8];
    {
        const float4* p = reinterpret_cast<const float4*>(a_kern + ((lane & 15) << 3));
        float4 a0 = p[0], a1 = p[1];
        ak[0] = a0.x; ak[1] = a0.y; ak[2] = a0.z; ak[3] = a0.w;
        ak[4] = a1.x; ak[5] = a1.y; ak[6] = a1.z; ak[7] = a1.w;
    }
    float asrc[8];
    load8bf(T + (size_t)n * TVAR + c0, asrc);

    float m = -INFINITY, s = 0.f;
    float acc[8] = {0, 0, 0, 0, 0, 0, 0, 0};

    // prefetch state for edge q
    int mk_n = 0;
    uint4 va_n, vt_n, vm_n, vtm_n;
    if (e0 < e1) {
        int e = eids[e0]; int t = tgt[e]; mk_n = mask[e];
        va_n  = *(const uint4*)(eam + (size_t)e * 1024 + c0);
        vt_n  = *(const uint4*)(T + (size_t)t * TVAR + 512 + c0);
        vm_n  = *(const uint4*)(eam + (size_t)e * 1024 + 512 + c0);
        vtm_n = *(const uint4*)(T + (size_t)t * TVAR + 1024 + c0);
    }
    for (int q = e0; q < e1; ++q) {
        uint4 va = va_n, vt = vt_n, vm = vm_n, vtm = vtm_n;
        int mk = mk_n;
        int q2 = q + 1;
        if (q2 < e1) {   // issue next edge's loads before current compute
            int e = eids[q2]; int t = tgt[e]; mk_n = mask[e];
            va_n  = *(const uint4*)(eam + (size_t)e * 1024 + c0);
            vt_n  = *(const uint4*)(T + (size_t)t * TVAR + 512 + c0);
            vm_n  = *(const uint4*)(eam + (size_t)e * 1024 + 512 + c0);
            vtm_n = *(const uint4*)(T + (size_t)t * TVAR + 1024 + c0);
        }
        float ea[8], tt[8], em[8], tm[8];
        unpack8(va, ea); unpack8(vt, tt); unpack8(vm, em); unpack8(vtm, tm);
        float p = 0.f;
#pragma unroll
        for (int j = 0; j < 8; ++j) {
            float v = asrc[j] + ea[j] + tt[j];
            v = (v > 0.f) ? v : 0.2f * v;          // leaky_relu 0.2
            p = fmaf(v, ak[j], p);
        }
        p += __shfl_xor(p, 1);
        p += __shfl_xor(p, 2);
        p += __shfl_xor(p, 4);
        p += __shfl_xor(p, 8);                     // per-head logit (16-lane group)
        p = mk ? p : -INFINITY;                    // masked edge: -inf logit (branchless)
        float mn = fmaxf(m, p);
        bool live = (mn != -INFINITY);
        float wgt = live ? __expf(p - mn) : 0.f;   // p=-inf -> 0; guards NaN when mn=-inf
        float sc  = live ? __expf(m - mn) : 0.f;   // m=-inf -> 0
        s = s * sc + wgt;
#pragma unroll
        for (int j = 0; j < 8; ++j) acc[j] = acc[j] * sc + wgt * (em[j] + tm[j]);
        m = mn;
    }
    if (e1 > e0 && m == -INFINITY) {
        // dead node (all edges masked): ref gives uniform attention over ALL its edges
        s = (float)(e1 - e0);
        for (int q = e0; q < e1; ++q) {
            int e = eids[q]; int t = tgt[e];
            float em[8], tm[8];
            load8bf(eam + (size_t)e * 1024 + 512 + c0, em);
            load8bf(T + (size_t)t * TVAR + 1024 + c0, tm);
#pragma unroll
            for (int j = 0; j < 8; ++j) acc[j] += em[j] + tm[j];
        }
    }
    float inv = (e1 > e0) ? (1.f / s) : 0.f;
    float r[8];
#pragma unroll
    for (int j = 0; j < 8; ++j) {
        float v = acc[j] * inv;
        v += __shfl_xor(v, 16);
        v += __shfl_xor(v, 32);                    // sum 4 heads (same channel)
        r[j] = v;
    }
    bool upd = iter < n_states[n];
    if (lane < 16) {
        float out[8];
#pragma unroll
        for (int j = 0; j < 8; ++j)
            out[j] = upd ? tanhf(r[j]) : h_old[(size_t)n * HIDD + c0 + j];
        float4* ph = reinterpret_cast<float4*>(h_new + (size_t)n * HIDD + c0);
        float4 o0, o1;
        o0.x = out[0]; o0.y = out[1]; o0.z = out[2]; o0.w = out[3];
        o1.x = out[4]; o1.y = out[5]; o1.z = out[6]; o1.w = out[7];
        ph[0] = o0; ph[1] = o1;
        ushort4 b0, b1;
        b0.x = f2bf(out[0]); b0.y = f2bf(out[1]); b0.z = f2bf(out[2]); b0.w = f2bf(out[3]);
        b1.x = f2bf(out[4]); b1.y = f2bf(out[5]); b1.z = f2bf(out[6]); b1.w = f2bf(out[7]);
        ushort4* pb = reinterpret_cast<ushort4*>(h_new_bf + (size_t)n * HIDD + c0);
        pb[0] = b0; pb[1] = b1;
    }
}

// ---------------- out = h[cs] @ W_g ----------------
__global__ void k_out(const float* __restrict__ h, const int* __restrict__ cs,
                      const float* __restrict__ Wg, float* __restrict__ out) {
    int idx = blockIdx.x * blockDim.x + threadIdx.x;   // B*ENC threads
    int b = idx >> 6, c = idx & 63;
    int n = cs[b];
    float s = 0.f;
#pragma unroll
    for (int k = 0; k < HIDD; ++k) s += h[(size_t)n * HIDD + k] * Wg[k * ENCD + c];
    out[idx] = s;
}

extern "C" void kernel_launch(void* const* d_in, const int* in_sizes, int n_in,
                              void* d_out, int out_size, void* d_ws, size_t ws_size,
                              hipStream_t stream) {
    const float* nf  = (const float*)d_in[0];
    const float* ef  = (const float*)d_in[1];
    const int* eidx  = (const int*)d_in[2];
    const int* cs    = (const int*)d_in[3];
    const int* nst   = (const int*)d_in[4];
    const float* Wh  = (const float*)d_in[5];
    const float* We  = (const float*)d_in[6];
    const float* Wa  = (const float*)d_in[7];
    const float* Wm  = (const float*)d_in[8];
    const float* akn = (const float*)d_in[9];
    const float* Wg  = (const float*)d_in[10];
    const int* src = eidx;
    const int* tgt = eidx + N_EDGES;

    char* w = (char*)d_ws;
    size_t off = 0;
    auto alloc = [&](size_t bytes) -> void* {
        void* p = w + off;
        off = (off + bytes + 255) & ~(size_t)255;
        return p;
    };
    float* hA       = (float*)alloc((size_t)N_NODES * HIDD * 4);
    float* hB       = (float*)alloc((size_t)N_NODES * HIDD * 4);
    ushort_t* hAbf  = (ushort_t*)alloc((size_t)N_NODES * HIDD * 2);
    ushort_t* hBbf  = (ushort_t*)alloc((size_t)N_NODES * HIDD * 2);
    ushort_t* h0bf  = (ushort_t*)alloc((size_t)N_NODES * HIDD * 2);
    ushort_t* eh    = (ushort_t*)alloc((size_t)N_EDGES * HIDD * 2);
    int* mask       = (int*)alloc((size_t)N_EDGES * 4);
    ushort_t* eam   = (ushort_t*)alloc((size_t)N_EDGES * 1024 * 2);
    ushort_t* Tfix  = (ushort_t*)alloc((size_t)N_NODES * TVAR * 2);
    ushort_t* Tcur  = (ushort_t*)alloc((size_t)N_NODES * TVAR * 2);
    ushort_t* WvarT = (ushort_t*)alloc((size_t)TVAR * 128 * 2);
    ushort_t* WfixT = (ushort_t*)alloc((size_t)TVAR * 128 * 2);
    ushort_t* WeamT = (ushort_t*)alloc((size_t)1024 * 128 * 2);
    int* deg        = (int*)alloc((size_t)N_NODES * 4);
    int* offs       = (int*)alloc((size_t)(N_NODES + 1) * 4);
    int* cursor     = (int*)alloc((size_t)N_NODES * 4);
    int* eids       = (int*)alloc((size_t)N_EDGES * 4);
    (void)ws_size; (void)in_sizes; (void)n_in; (void)out_size;  // ~110 MB used

    k_pack<<<(128 * TVAR) / 256, 256, 0, stream>>>(Wa, Wm, WvarT, WfixT, WeamT);
    k_h0<<<(N_NODES * HIDD) / 256, 256, 0, stream>>>(nf, Wh, h0bf, hA, hAbf);
    k_ehid<<<(N_EDGES * HIDD) / 256, 256, 0, stream>>>(ef, We, eh);
    k_mask<<<N_EDGES / 256, 256, 0, stream>>>(ef, mask);

    dim3 g_eam(1024 / 64, N_EDGES / 64);
    k_mgemm<false><<<g_eam, 256, 0, stream>>>(eh, WeamT, nullptr, eam, 1024);
    dim3 g_tab(TVAR / 64, N_NODES / 64);
    k_mgemm<false><<<g_tab, 256, 0, stream>>>(h0bf, WfixT, nullptr, Tfix, TVAR);

    k_zero<<<N_NODES / 256, 256, 0, stream>>>(deg);
    k_count<<<N_EDGES / 256, 256, 0, stream>>>(src, deg);
    k_scan<<<1, 1024, 0, stream>>>(deg, offs, cursor);
    k_fill<<<N_EDGES / 256, 256, 0, stream>>>(src, cursor, eids);

    float* hcur = hA; float* hnext = hB;
    ushort_t* hcbf = hAbf; ushort_t* hnbf = hBbf;
    for (int i = 0; i < MAXS; ++i) {
        k_mgemm<true><<<g_tab, 256, 0, stream>>>(hcbf, WvarT, Tfix, Tcur, TVAR);
        k_edge<<<N_NODES / 4, 256, 0, stream>>>(Tcur, eam, tgt, offs, eids, mask, akn, nst,
                                                hcur, hnext, hnbf, i);
        float* tmp = hcur; hcur = hnext; hnext = tmp;
        ushort_t* tb = hcbf; hcbf = hnbf; hnbf = tb;
    }
    k_out<<<(BATCH * ENCD) / 256, 256, 0, stream>>>(hcur, cs, Wg, (float*)d_out);
}

// Round 7
// 602.040 us; speedup vs baseline: 1.3370x; 1.1090x over previous
//
#include <hip/hip_runtime.h>
#include <hip/hip_bf16.h>

// Problem constants (fixed by the reference)
#define N_NODES 4096
#define N_EDGES 32768
#define BATCH   1024
#define NFEAT   32
#define EFEAT   16
#define ENCD    64
#define HIDD    128
#define HEADS   4
#define HID4    512
#define MAXS    10
#define TVAR    1536   // 3*HID4: [src-attn | tgt-attn | tgt-msg] node tables

typedef unsigned short ushort_t;
typedef __bf16 bf16x8 __attribute__((ext_vector_type(8)));
typedef float f32x4 __attribute__((ext_vector_type(4)));

static __device__ __forceinline__ float bfbits2f(unsigned int hi16) {
    return __uint_as_float(hi16);
}
static __device__ __forceinline__ void unpack8(uint4 v, float* f) {
    f[0] = bfbits2f(v.x << 16); f[1] = bfbits2f(v.x & 0xffff0000u);
    f[2] = bfbits2f(v.y << 16); f[3] = bfbits2f(v.y & 0xffff0000u);
    f[4] = bfbits2f(v.z << 16); f[5] = bfbits2f(v.z & 0xffff0000u);
    f[6] = bfbits2f(v.w << 16); f[7] = bfbits2f(v.w & 0xffff0000u);
}
static __device__ __forceinline__ void load8bf(const ushort_t* p, float* f) {
    unpack8(*reinterpret_cast<const uint4*>(p), f);
}
static __device__ __forceinline__ unsigned short f2bf(float x) {
    __hip_bfloat16 h = __float2bfloat16(x);
    return *reinterpret_cast<unsigned short*>(&h);
}
static __device__ __forceinline__ unsigned addpack(unsigned s, unsigned a) {
    float s0 = bfbits2f(s << 16), s1 = bfbits2f(s & 0xffff0000u);
    float a0 = bfbits2f(a << 16), a1 = bfbits2f(a & 0xffff0000u);
    unsigned r0 = f2bf(s0 + a0), r1 = f2bf(s1 + a1);
    return r0 | (r1 << 16);
}

// Fragment-swizzled layout for a [rows][K] bf16 operand of mfma_f32_16x16x32_bf16:
//   element (row, k) lives at ((panel*NQ + q)*64 + kgrp*16 + r)*8 + j
//   panel=row>>4, r=row&15, q=k>>5, kgrp=(k>>3)&3, j=k&7
// A wave's fragment load is then base + lane*16B  ->  one contiguous 1KB transaction.

// ---- Wcomb_sw = swizzle(pad32(We @ Weam)), Weam[k][c] = c<512 ? Wa[256+k][c] : Wm[k][c-512]
__global__ void k_comp_eam(const float* __restrict__ We, const float* __restrict__ Wa,
                           const float* __restrict__ Wm, ushort_t* __restrict__ out) {
    int idx = blockIdx.x * blockDim.x + threadIdx.x;   // 64 panels * 64 lanes
    int p = idx >> 6, l = idx & 63;
    int c = p * 16 + (l & 15);
    int k0 = (l >> 4) << 3;
    float s[8] = {0, 0, 0, 0, 0, 0, 0, 0};
    for (int kk = 0; kk < 128; ++kk) {
        float wv = (c < 512) ? Wa[(256 + kk) * HID4 + c] : Wm[kk * HID4 + (c - 512)];
#pragma unroll
        for (int j = 0; j < 8; ++j) {
            int k = k0 + j;
            if (k < 16) s[j] += We[k * 128 + kk] * wv;
        }
    }
#pragma unroll
    for (int j = 0; j < 8; ++j) out[(size_t)idx * 8 + j] = f2bf(s[j]);
}

// ---- WfixC_sw = swizzle(Wh @ Wfix), K=32 exact
__global__ void k_comp_fix(const float* __restrict__ Wh, const float* __restrict__ Wa,
                           const float* __restrict__ Wm, ushort_t* __restrict__ out) {
    int idx = blockIdx.x * blockDim.x + threadIdx.x;   // 96 panels * 64 lanes
    int p = idx >> 6, l = idx & 63;
    int c = p * 16 + (l & 15);
    int k0 = (l >> 4) << 3;
    float s[8] = {0, 0, 0, 0, 0, 0, 0, 0};
    for (int kk = 0; kk < 128; ++kk) {
        float wv = (c < 512) ? Wa[(128 + kk) * HID4 + c]
                 : (c < 1024) ? Wa[(512 + kk) * HID4 + (c - 512)]
                              : Wm[(256 + kk) * HID4 + (c - 1024)];
#pragma unroll
        for (int j = 0; j < 8; ++j) s[j] += Wh[(k0 + j) * 128 + kk] * wv;
    }
#pragma unroll
    for (int j = 0; j < 8; ++j) out[(size_t)idx * 8 + j] = f2bf(s[j]);
}

// ---- Wvar_sw = swizzle(Wvar[128][1536])
__global__ void k_pack_var(const float* __restrict__ Wa, const float* __restrict__ Wm,
                           ushort_t* __restrict__ out) {
    int idx = blockIdx.x * blockDim.x + threadIdx.x;   // 96 panels * 4 q * 64 lanes
    int p = idx >> 8, rem = idx & 255;
    int q = rem >> 6, l = rem & 63;
    int c = p * 16 + (l & 15);
    int k0 = q * 32 + ((l >> 4) << 3);
#pragma unroll
    for (int j = 0; j < 8; ++j) {
        int k = k0 + j;
        float v = (c < 512) ? Wa[k * HID4 + c]
                : (c < 1024) ? Wa[(384 + k) * HID4 + (c - 512)]
                             : Wm[(128 + k) * HID4 + (c - 1024)];
        out[(size_t)idx * 8 + j] = f2bf(v);
    }
}

// ---- efp_sw = swizzle(pad32(ef[E][16]))
__global__ void k_prep_ef(const float* __restrict__ ef, ushort_t* __restrict__ out) {
    int idx = blockIdx.x * blockDim.x + threadIdx.x;   // 2048 panels * 64 lanes
    int p = idx >> 6, l = idx & 63;
    int e = p * 16 + (l & 15);
    int k0 = (l >> 4) << 3;
#pragma unroll
    for (int j = 0; j < 8; ++j) {
        int k = k0 + j;
        out[(size_t)idx * 8 + j] = (k < 16) ? f2bf(ef[e * EFEAT + k]) : (ushort_t)0;
    }
}

// ---- nfp_sw = swizzle(nf[N][32]), K=32 exact
__global__ void k_prep_nf(const float* __restrict__ nf, ushort_t* __restrict__ out) {
    int idx = blockIdx.x * blockDim.x + threadIdx.x;   // 256 panels * 64 lanes
    int p = idx >> 6, l = idx & 63;
    int n = p * 16 + (l & 15);
    int k0 = (l >> 4) << 3;
#pragma unroll
    for (int j = 0; j < 8; ++j)
        out[(size_t)idx * 8 + j] = f2bf(nf[n * NFEAT + k0 + j]);
}

// ---- h0 = nf @ W_h : hA f32 (natural) + hAbf (swizzled)
__global__ void k_h0(const float* __restrict__ nf, const float* __restrict__ Wh,
                     float* __restrict__ hA, ushort_t* __restrict__ hAbf) {
    int idx = blockIdx.x * blockDim.x + threadIdx.x;   // N*HID
    int n = idx >> 7, c = idx & 127;
    float s = 0.f;
#pragma unroll
    for (int k = 0; k < NFEAT; ++k) s += nf[n * NFEAT + k] * Wh[k * HIDD + c];
    hA[idx] = s;
    int p = n >> 4, r = n & 15, q = c >> 5, kg = (c >> 3) & 3, j = c & 7;
    hAbf[(size_t)(((p * 4 + q) * 64) + kg * 16 + r) * 8 + j] = f2bf(s);
}

// ---- attn mask
__global__ void k_mask(const float* __restrict__ ef, int* __restrict__ mask) {
    int e = blockIdx.x * blockDim.x + threadIdx.x;
    int m = 0;
#pragma unroll
    for (int k = 0; k < EFEAT; ++k) m |= (ef[e * EFEAT + k] != 0.f);
    mask[e] = m;
}

// ------------- K=32 swizzled GEMM: C[M][NC] = bf16(A_sw @ B_sw) -------------
// block 256 = 4 waves; wave = 64 rows (4 panels) x 64 cols (4 panels); block = 256 rows.
__global__ __launch_bounds__(256) void k_gemm32(const ushort_t* __restrict__ A_sw,
                                                const ushort_t* __restrict__ B_sw,
                                                ushort_t* __restrict__ C, int NC) {
    __shared__ ushort_t lds[4][64][64];   // 32 KB
    const int tid = threadIdx.x;
    const int l = tid & 63;
    const int w = tid >> 6;
    const int mpb = blockIdx.y * 16 + w * 4;
    const int cpb = blockIdx.x * 4;

    bf16x8 a[4], b[4];
#pragma unroll
    for (int mi = 0; mi < 4; ++mi)
        a[mi] = *(const bf16x8*)(A_sw + (size_t)((mpb + mi) * 64 + l) * 8);
#pragma unroll
    for (int ct = 0; ct < 4; ++ct)
        b[ct] = *(const bf16x8*)(B_sw + (size_t)((cpb + ct) * 64 + l) * 8);

    const int rb = (l >> 4) << 2, lc = l & 15;
#pragma unroll
    for (int mi = 0; mi < 4; ++mi)
#pragma unroll
        for (int ct = 0; ct < 4; ++ct) {
            f32x4 c = {0.f, 0.f, 0.f, 0.f};
            c = __builtin_amdgcn_mfma_f32_16x16x32_bf16(a[mi], b[ct], c, 0, 0, 0);
#pragma unroll
            for (int r = 0; r < 4; ++r)
                lds[w][mi * 16 + rb + r][ct * 16 + lc] = f2bf(c[r]);
        }
    __syncthreads();
#pragma unroll
    for (int i = 0; i < 8; ++i) {
        int ch = (i << 6) + l;
        int row = ch >> 3, co = (ch & 7) << 3;
        int grow = blockIdx.y * 256 + w * 64 + row;
        size_t gidx = (size_t)grow * NC + blockIdx.x * 64 + co;
        *(uint4*)(C + gidx) = *(const uint4*)(&lds[w][row][co]);
    }
}

// ------------- K=128 swizzled GEMM: C = bf16(A_sw @ B_sw + Cadd) -------------
// block 256 = 4 waves; wave = 32 rows (2 panels) x 64 cols; block = 128 rows.
__global__ __launch_bounds__(256) void k_gemm128(const ushort_t* __restrict__ A_sw,
                                                 const ushort_t* __restrict__ B_sw,
                                                 const ushort_t* __restrict__ Cadd,
                                                 ushort_t* __restrict__ C, int NC) {
    __shared__ ushort_t lds[4][32][64];   // 16 KB
    const int tid = threadIdx.x;
    const int l = tid & 63;
    const int w = tid >> 6;
    const int mpb = blockIdx.y * 8 + w * 2;
    const int cpb = blockIdx.x * 4;

    bf16x8 a[2][4], b[4][4];
#pragma unroll
    for (int mi = 0; mi < 2; ++mi)
#pragma unroll
        for (int q = 0; q < 4; ++q)
            a[mi][q] = *(const bf16x8*)(A_sw + (size_t)(((mpb + mi) * 4 + q) * 64 + l) * 8);
#pragma unroll
    for (int ct = 0; ct < 4; ++ct)
#pragma unroll
        for (int q = 0; q < 4; ++q)
            b[ct][q] = *(const bf16x8*)(B_sw + (size_t)(((cpb + ct) * 4 + q) * 64 + l) * 8);

    const int rb = (l >> 4) << 2, lc = l & 15;
#pragma unroll
    for (int mi = 0; mi < 2; ++mi)
#pragma unroll
        for (int ct = 0; ct < 4; ++ct) {
            f32x4 c = {0.f, 0.f, 0.f, 0.f};
#pragma unroll
            for (int q = 0; q < 4; ++q)
                c = __builtin_amdgcn_mfma_f32_16x16x32_bf16(a[mi][q], b[ct][q], c, 0, 0, 0);
#pragma unroll
            for (int r = 0; r < 4; ++r)
                lds[w][mi * 16 + rb + r][ct * 16 + lc] = f2bf(c[r]);
        }
    __syncthreads();
#pragma unroll
    for (int i = 0; i < 4; ++i) {
        int ch = (i << 6) + l;
        int row = ch >> 3, co = (ch & 7) << 3;
        int grow = blockIdx.y * 128 + w * 32 + row;
        size_t gidx = (size_t)grow * NC + blockIdx.x * 64 + co;
        uint4 sv = *(const uint4*)(&lds[w][row][co]);
        uint4 av = *(const uint4*)(Cadd + gidx);
        sv.x = addpack(sv.x, av.x);
        sv.y = addpack(sv.y, av.y);
        sv.z = addpack(sv.z, av.z);
        sv.w = addpack(sv.w, av.w);
        *(uint4*)(C + gidx) = sv;
    }
}

// ---------------- CSR build ----------------
__global__ void k_zero(int* p) { p[blockIdx.x * blockDim.x + threadIdx.x] = 0; }
__global__ void k_count(const int* __restrict__ src, int* __restrict__ deg) {
    int e = blockIdx.x * blockDim.x + threadIdx.x;
    atomicAdd(&deg[src[e]], 1);
}
__global__ __launch_bounds__(1024) void k_scan(const int* __restrict__ deg,
                                               int* __restrict__ offs, int* __restrict__ cursor) {
    __shared__ int sm[1024];
    int t = threadIdx.x;
    int d0 = deg[t * 4], d1 = deg[t * 4 + 1], d2 = deg[t * 4 + 2], d3 = deg[t * 4 + 3];
    int s = d0 + d1 + d2 + d3;
    sm[t] = s; __syncthreads();
    for (int o = 1; o < 1024; o <<= 1) {
        int v = (t >= o) ? sm[t - o] : 0;
        __syncthreads();
        sm[t] += v;
        __syncthreads();
    }
    int run = sm[t] - s;
    offs[t * 4] = run;     cursor[t * 4] = run;     run += d0;
    offs[t * 4 + 1] = run; cursor[t * 4 + 1] = run; run += d1;
    offs[t * 4 + 2] = run; cursor[t * 4 + 2] = run; run += d2;
    offs[t * 4 + 3] = run; cursor[t * 4 + 3] = run;
    if (t == 1023) offs[4096] = run + d3;
}
__global__ void k_fill(const int* __restrict__ src, int* __restrict__ cursor, int* __restrict__ eids) {
    int e = blockIdx.x * blockDim.x + threadIdx.x;
    int pos = atomicAdd(&cursor[src[e]], 1);
    eids[pos] = e;
}

// ------ fused edge pass (one wave per node), depth-1 prefetch, swizzled bf16 h output ------
__global__ __launch_bounds__(256) void k_edge(const ushort_t* __restrict__ T,    // [N][1536] bf16
                                              const ushort_t* __restrict__ eam,  // [E][1024] bf16
                                              const int* __restrict__ tgt,
                                              const int* __restrict__ offs,
                                              const int* __restrict__ eids,
                                              const int* __restrict__ mask,
                                              const float* __restrict__ a_kern,
                                              const int* __restrict__ n_states,
                                              const float* __restrict__ h_old,
                                              float* __restrict__ h_new,
                                              ushort_t* __restrict__ h_new_bf, int iter) {
    const int n = (blockIdx.x << 2) + (threadIdx.x >> 6);
    const int lane = threadIdx.x & 63;
    const int c0 = lane << 3;
    const int e0 = offs[n], e1 = offs[n + 1];

    float ak[8];
    {
        const float4* p = reinterpret_cast<const float4*>(a_kern + ((lane & 15) << 3));
        float4 a0 = p[0], a1 = p[1];
        ak[0] = a0.x; ak[1] = a0.y; ak[2] = a0.z; ak[3] = a0.w;
        ak[4] = a1.x; ak[5] = a1.y; ak[6] = a1.z; ak[7] = a1.w;
    }
    float asrc[8];
    load8bf(T + (size_t)n * TVAR + c0, asrc);

    float m = -INFINITY, s = 0.f;
    float acc[8] = {0, 0, 0, 0, 0, 0, 0, 0};

    int mk_n = 0;
    uint4 va_n, vt_n, vm_n, vtm_n;
    if (e0 < e1) {
        int e = eids[e0]; int t = tgt[e]; mk_n = mask[e];
        va_n  = *(const uint4*)(eam + (size_t)e * 1024 + c0);
        vt_n  = *(const uint4*)(T + (size_t)t * TVAR + 512 + c0);
        vm_n  = *(const uint4*)(eam + (size_t)e * 1024 + 512 + c0);
        vtm_n = *(const uint4*)(T + (size_t)t * TVAR + 1024 + c0);
    }
    for (int q = e0; q < e1; ++q) {
        uint4 va = va_n, vt = vt_n, vm = vm_n, vtm = vtm_n;
        int mk = mk_n;
        int q2 = q + 1;
        if (q2 < e1) {
            int e = eids[q2]; int t = tgt[e]; mk_n = mask[e];
            va_n  = *(const uint4*)(eam + (size_t)e * 1024 + c0);
            vt_n  = *(const uint4*)(T + (size_t)t * TVAR + 512 + c0);
            vm_n  = *(const uint4*)(eam + (size_t)e * 1024 + 512 + c0);
            vtm_n = *(const uint4*)(T + (size_t)t * TVAR + 1024 + c0);
        }
        float ea[8], tt[8], em[8], tm[8];
        unpack8(va, ea); unpack8(vt, tt); unpack8(vm, em); unpack8(vtm, tm);
        float p = 0.f;
#pragma unroll
        for (int j = 0; j < 8; ++j) {
            float v = asrc[j] + ea[j] + tt[j];
            v = (v > 0.f) ? v : 0.2f * v;          // leaky_relu 0.2
            p = fmaf(v, ak[j], p);
        }
        p += __shfl_xor(p, 1);
        p += __shfl_xor(p, 2);
        p += __shfl_xor(p, 4);
        p += __shfl_xor(p, 8);                     // per-head logit (16-lane group)
        p = mk ? p : -INFINITY;
        float mn = fmaxf(m, p);
        bool live = (mn != -INFINITY);
        float wgt = live ? __expf(p - mn) : 0.f;
        float sc  = live ? __expf(m - mn) : 0.f;
        s = s * sc + wgt;
#pragma unroll
        for (int j = 0; j < 8; ++j) acc[j] = acc[j] * sc + wgt * (em[j] + tm[j]);
        m = mn;
    }
    if (e1 > e0 && m == -INFINITY) {
        s = (float)(e1 - e0);
        for (int q = e0; q < e1; ++q) {
            int e = eids[q]; int t = tgt[e];
            float em[8], tm[8];
            load8bf(eam + (size_t)e * 1024 + 512 + c0, em);
            load8bf(T + (size_t)t * TVAR + 1024 + c0, tm);
#pragma unroll
            for (int j = 0; j < 8; ++j) acc[j] += em[j] + tm[j];
        }
    }
    float inv = (e1 > e0) ? (1.f / s) : 0.f;
    float r[8];
#pragma unroll
    for (int j = 0; j < 8; ++j) {
        float v = acc[j] * inv;
        v += __shfl_xor(v, 16);
        v += __shfl_xor(v, 32);
        r[j] = v;
    }
    bool upd = iter < n_states[n];
    if (lane < 16) {
        float out[8];
#pragma unroll
        for (int j = 0; j < 8; ++j)
            out[j] = upd ? tanhf(r[j]) : h_old[(size_t)n * HIDD + c0 + j];
        float4* ph = reinterpret_cast<float4*>(h_new + (size_t)n * HIDD + c0);
        float4 o0, o1;
        o0.x = out[0]; o0.y = out[1]; o0.z = out[2]; o0.w = out[3];
        o1.x = out[4]; o1.y = out[5]; o1.z = out[6]; o1.w = out[7];
        ph[0] = o0; ph[1] = o1;
        // swizzled bf16 store: p,r from node; q,kg from lane
        int p = n >> 4, rr = n & 15, q = lane >> 2, kg = lane & 3;
        uint4 u;
        u.x = (unsigned)f2bf(out[0]) | ((unsigned)f2bf(out[1]) << 16);
        u.y = (unsigned)f2bf(out[2]) | ((unsigned)f2bf(out[3]) << 16);
        u.z = (unsigned)f2bf(out[4]) | ((unsigned)f2bf(out[5]) << 16);
        u.w = (unsigned)f2bf(out[6]) | ((unsigned)f2bf(out[7]) << 16);
        *(uint4*)(h_new_bf + (size_t)(((p * 4 + q) * 64) + kg * 16 + rr) * 8) = u;
    }
}

// ---------------- out = h[cs] @ W_g ----------------
__global__ void k_out(const float* __restrict__ h, const int* __restrict__ cs,
                      const float* __restrict__ Wg, float* __restrict__ out) {
    int idx = blockIdx.x * blockDim.x + threadIdx.x;   // B*ENC
    int b = idx >> 6, c = idx & 63;
    int n = cs[b];
    float s = 0.f;
#pragma unroll
    for (int k = 0; k < HIDD; ++k) s += h[(size_t)n * HIDD + k] * Wg[k * ENCD + c];
    out[idx] = s;
}

extern "C" void kernel_launch(void* const* d_in, const int* in_sizes, int n_in,
                              void* d_out, int out_size, void* d_ws, size_t ws_size,
                              hipStream_t stream) {
    const float* nf  = (const float*)d_in[0];
    const float* ef  = (const float*)d_in[1];
    const int* eidx  = (const int*)d_in[2];
    const int* cs    = (const int*)d_in[3];
    const int* nst   = (const int*)d_in[4];
    const float* Wh  = (const float*)d_in[5];
    const float* We  = (const float*)d_in[6];
    const float* Wa  = (const float*)d_in[7];
    const float* Wm  = (const float*)d_in[8];
    const float* akn = (const float*)d_in[9];
    const float* Wg  = (const float*)d_in[10];
    const int* src = eidx;
    const int* tgt = eidx + N_EDGES;

    char* w = (char*)d_ws;
    size_t off = 0;
    auto alloc = [&](size_t bytes) -> void* {
        void* p = w + off;
        off = (off + bytes + 255) & ~(size_t)255;
        return p;
    };
    float* hA        = (float*)alloc((size_t)N_NODES * HIDD * 4);
    float* hB        = (float*)alloc((size_t)N_NODES * HIDD * 4);
    ushort_t* hAbf   = (ushort_t*)alloc((size_t)N_NODES * HIDD * 2);
    ushort_t* hBbf   = (ushort_t*)alloc((size_t)N_NODES * HIDD * 2);
    int* mask        = (int*)alloc((size_t)N_EDGES * 4);
    ushort_t* eam    = (ushort_t*)alloc((size_t)N_EDGES * 1024 * 2);   // 64 MB
    ushort_t* Tfix   = (ushort_t*)alloc((size_t)N_NODES * TVAR * 2);   // 12 MB
    ushort_t* Tcur   = (ushort_t*)alloc((size_t)N_NODES * TVAR * 2);   // 12 MB
    ushort_t* Wcomb  = (ushort_t*)alloc((size_t)64 * 64 * 8 * 2);      // 64 KB
    ushort_t* WfixC  = (ushort_t*)alloc((size_t)96 * 64 * 8 * 2);      // 96 KB
    ushort_t* WvarSw = (ushort_t*)alloc((size_t)96 * 4 * 64 * 8 * 2);  // 384 KB
    ushort_t* efp    = (ushort_t*)alloc((size_t)2048 * 64 * 8 * 2);    // 2 MB
    ushort_t* nfp    = (ushort_t*)alloc((size_t)256 * 64 * 8 * 2);     // 256 KB
    int* deg         = (int*)alloc((size_t)N_NODES * 4);
    int* offs        = (int*)alloc((size_t)(N_NODES + 1) * 4);
    int* cursor      = (int*)alloc((size_t)N_NODES * 4);
    int* eids        = (int*)alloc((size_t)N_EDGES * 4);
    (void)ws_size; (void)in_sizes; (void)n_in; (void)out_size;  // ~95 MB used

    k_comp_eam<<<16, 256, 0, stream>>>(We, Wa, Wm, Wcomb);
    k_comp_fix<<<24, 256, 0, stream>>>(Wh, Wa, Wm, WfixC);
    k_pack_var<<<96, 256, 0, stream>>>(Wa, Wm, WvarSw);
    k_prep_ef<<<512, 256, 0, stream>>>(ef, efp);
    k_prep_nf<<<64, 256, 0, stream>>>(nf, nfp);
    k_h0<<<(N_NODES * HIDD) / 256, 256, 0, stream>>>(nf, Wh, hA, hAbf);
    k_mask<<<N_EDGES / 256, 256, 0, stream>>>(ef, mask);

    // eam[E][1024] = efp @ Wcomb (K=16 padded to 32)
    k_gemm32<<<dim3(1024 / 64, N_EDGES / 256), 256, 0, stream>>>(efp, Wcomb, eam, 1024);
    // Tfix[N][1536] = nfp @ WfixC (K=32)
    k_gemm32<<<dim3(TVAR / 64, N_NODES / 256), 256, 0, stream>>>(nfp, WfixC, Tfix, TVAR);

    k_zero<<<N_NODES / 256, 256, 0, stream>>>(deg);
    k_count<<<N_EDGES / 256, 256, 0, stream>>>(src, deg);
    k_scan<<<1, 1024, 0, stream>>>(deg, offs, cursor);
    k_fill<<<N_EDGES / 256, 256, 0, stream>>>(src, cursor, eids);

    float* hcur = hA; float* hnext = hB;
    ushort_t* hcbf = hAbf; ushort_t* hnbf = hBbf;
    for (int i = 0; i < MAXS; ++i) {
        k_gemm128<<<dim3(TVAR / 64, N_NODES / 128), 256, 0, stream>>>(hcbf, WvarSw, Tfix, Tcur, TVAR);
        k_edge<<<N_NODES / 4, 256, 0, stream>>>(Tcur, eam, tgt, offs, eids, mask, akn, nst,
                                                hcur, hnext, hnbf, i);
        float* tmp = hcur; hcur = hnext; hnext = tmp;
        ushort_t* tb = hcbf; hcbf = hnbf; hnbf = tb;
    }
    k_out<<<(BATCH * ENCD) / 256, 256, 0, stream>>>(hcur, cs, Wg, (float*)d_out);
}

// Round 9
// 497.620 us; speedup vs baseline: 1.6175x; 1.2098x over previous
//
#include <hip/hip_runtime.h>
#include <hip/hip_bf16.h>

// Problem constants (fixed by the reference)
#define N_NODES 4096
#define N_EDGES 32768
#define BATCH   1024
#define NFEAT   32
#define EFEAT   16
#define ENCD    64
#define HIDD    128
#define HEADS   4
#define HID4    512
#define MAXS    10
#define TVAR    1536   // 3*HID4: [src-attn | tgt-attn | tgt-msg] node tables

typedef unsigned short ushort_t;
typedef __bf16 bf16x8 __attribute__((ext_vector_type(8)));
typedef float f32x4 __attribute__((ext_vector_type(4)));

static __device__ __forceinline__ float bfbits2f(unsigned int hi16) {
    return __uint_as_float(hi16);
}
static __device__ __forceinline__ void unpack8(uint4 v, float* f) {
    f[0] = bfbits2f(v.x << 16); f[1] = bfbits2f(v.x & 0xffff0000u);
    f[2] = bfbits2f(v.y << 16); f[3] = bfbits2f(v.y & 0xffff0000u);
    f[4] = bfbits2f(v.z << 16); f[5] = bfbits2f(v.z & 0xffff0000u);
    f[6] = bfbits2f(v.w << 16); f[7] = bfbits2f(v.w & 0xffff0000u);
}
static __device__ __forceinline__ void load8bf(const ushort_t* p, float* f) {
    unpack8(*reinterpret_cast<const uint4*>(p), f);
}
static __device__ __forceinline__ unsigned short f2bf(float x) {
    __hip_bfloat16 h = __float2bfloat16(x);
    return *reinterpret_cast<unsigned short*>(&h);
}
static __device__ __forceinline__ unsigned addpack(unsigned s, unsigned a) {
    float s0 = bfbits2f(s << 16), s1 = bfbits2f(s & 0xffff0000u);
    float a0 = bfbits2f(a << 16), a1 = bfbits2f(a & 0xffff0000u);
    unsigned r0 = f2bf(s0 + a0), r1 = f2bf(s1 + a1);
    return r0 | (r1 << 16);
}
static __device__ __forceinline__ uint4 pack8(const float* f) {
    uint4 u;
    u.x = (unsigned)f2bf(f[0]) | ((unsigned)f2bf(f[1]) << 16);
    u.y = (unsigned)f2bf(f[2]) | ((unsigned)f2bf(f[3]) << 16);
    u.z = (unsigned)f2bf(f[4]) | ((unsigned)f2bf(f[5]) << 16);
    u.w = (unsigned)f2bf(f[6]) | ((unsigned)f2bf(f[7]) << 16);
    return u;
}

// Fragment-swizzled layout for a [rows][K] bf16 operand of mfma_f32_16x16x32_bf16:
//   element (row, k) lives at ((panel*NQ + q)*64 + kgrp*16 + r)*8 + j
//   panel=row>>4, r=row&15, q=k>>5, kgrp=(k>>3)&3, j=k&7
// A wave's fragment load is then base + lane*16B  ->  one contiguous 1KB transaction.

// ---- Wcomb_sw = swizzle(pad32(We @ Weam)); one block per 16-col panel, LDS-staged.
__global__ __launch_bounds__(256) void k_comp_eam(const float* __restrict__ We,
                                                  const float* __restrict__ Wa,
                                                  const float* __restrict__ Wm,
                                                  ushort_t* __restrict__ out) {
    __shared__ float w_lds[128][17];
    const int t = threadIdx.x;
    const int p = blockIdx.x;          // 64 panels
    const int cl = t & 15, kbase = t >> 4;
    const int c = p * 16 + cl;
#pragma unroll
    for (int i = 0; i < 8; ++i) {      // 8 independent coalesced loads
        int kk = kbase + i * 16;
        w_lds[kk][cl] = (c < 512) ? Wa[(256 + kk) * HID4 + c] : Wm[kk * HID4 + (c - 512)];
    }
    __syncthreads();
    const int k = t >> 4;              // 0..15 (output K row)
    float s = 0.f;
    for (int kk = 0; kk < 128; ++kk)
        s = fmaf(We[k * 128 + kk], w_lds[kk][cl], s);
    int l = ((k >> 3) << 4) + cl, j = k & 7;
    out[((size_t)(p * 64 + l)) * 8 + j] = f2bf(s);
    if (t < 32) {                      // zero-pad k in [16,32): lanes 32..63
        uint4 z = {0, 0, 0, 0};
        *(uint4*)(out + ((size_t)(p * 64 + 32 + t)) * 8) = z;
    }
}

// ---- WfixC_sw = swizzle(Wh @ Wfix), K=32 exact; one block per 16-col panel.
__global__ __launch_bounds__(256) void k_comp_fix(const float* __restrict__ Wh,
                                                  const float* __restrict__ Wa,
                                                  const float* __restrict__ Wm,
                                                  ushort_t* __restrict__ out) {
    __shared__ float w_lds[128][17];
    const int t = threadIdx.x;
    const int p = blockIdx.x;          // 96 panels
    const int cl = t & 15, kbase = t >> 4;
    const int c = p * 16 + cl;
#pragma unroll
    for (int i = 0; i < 8; ++i) {
        int kk = kbase + i * 16;
        w_lds[kk][cl] = (c < 512) ? Wa[(128 + kk) * HID4 + c]
                      : (c < 1024) ? Wa[(512 + kk) * HID4 + (c - 512)]
                                   : Wm[(256 + kk) * HID4 + (c - 1024)];
    }
    __syncthreads();
    const int k1 = t >> 4, k2 = k1 + 16;
    float s1 = 0.f, s2 = 0.f;
    for (int kk = 0; kk < 128; ++kk) {
        float wv = w_lds[kk][cl];
        s1 = fmaf(Wh[k1 * 128 + kk], wv, s1);
        s2 = fmaf(Wh[k2 * 128 + kk], wv, s2);
    }
    int l1 = ((k1 >> 3) << 4) + cl, j1 = k1 & 7;
    int l2 = ((k2 >> 3) << 4) + cl, j2 = k2 & 7;
    out[((size_t)(p * 64 + l1)) * 8 + j1] = f2bf(s1);
    out[((size_t)(p * 64 + l2)) * 8 + j2] = f2bf(s2);
}

// ---- Wvar_sw = swizzle(Wvar[128][1536])
__global__ void k_pack_var(const float* __restrict__ Wa, const float* __restrict__ Wm,
                           ushort_t* __restrict__ out) {
    int idx = blockIdx.x * blockDim.x + threadIdx.x;   // 96 panels * 4 q * 64 lanes
    int p = idx >> 8, rem = idx & 255;
    int q = rem >> 6, l = rem & 63;
    int c = p * 16 + (l & 15);
    int k0 = q * 32 + ((l >> 4) << 3);
    float v[8];
#pragma unroll
    for (int j = 0; j < 8; ++j) {
        int k = k0 + j;
        v[j] = (c < 512) ? Wa[k * HID4 + c]
             : (c < 1024) ? Wa[(384 + k) * HID4 + (c - 512)]
                          : Wm[(128 + k) * HID4 + (c - 1024)];
    }
    *(uint4*)(out + (size_t)idx * 8) = pack8(v);
}

// ---- efp_sw = swizzle(pad32(ef[E][16]))
__global__ void k_prep_ef(const float* __restrict__ ef, ushort_t* __restrict__ out) {
    int idx = blockIdx.x * blockDim.x + threadIdx.x;   // 2048 panels * 64 lanes
    int p = idx >> 6, l = idx & 63;
    int e = p * 16 + (l & 15);
    int k0 = (l >> 4) << 3;
    float v[8];
#pragma unroll
    for (int j = 0; j < 8; ++j) {
        int k = k0 + j;
        v[j] = (k < 16) ? ef[e * EFEAT + k] : 0.f;
    }
    *(uint4*)(out + (size_t)idx * 8) = pack8(v);
}

// ---- nfp_sw = swizzle(nf[N][32]), K=32 exact
__global__ void k_prep_nf(const float* __restrict__ nf, ushort_t* __restrict__ out) {
    int idx = blockIdx.x * blockDim.x + threadIdx.x;   // 256 panels * 64 lanes
    int p = idx >> 6, l = idx & 63;
    int n = p * 16 + (l & 15);
    int k0 = (l >> 4) << 3;
    float v[8];
#pragma unroll
    for (int j = 0; j < 8; ++j) v[j] = nf[n * NFEAT + k0 + j];
    *(uint4*)(out + (size_t)idx * 8) = pack8(v);
}

// ---- h0 = nf @ W_h : hA f32 (natural) + hAbf (swizzled)
__global__ void k_h0(const float* __restrict__ nf, const float* __restrict__ Wh,
                     float* __restrict__ hA, ushort_t* __restrict__ hAbf) {
    int idx = blockIdx.x * blockDim.x + threadIdx.x;   // N*HID
    int n = idx >> 7, c = idx & 127;
    float s = 0.f;
#pragma unroll
    for (int k = 0; k < NFEAT; ++k) s += nf[n * NFEAT + k] * Wh[k * HIDD + c];
    hA[idx] = s;
    int p = n >> 4, r = n & 15, q = c >> 5, kg = (c >> 3) & 3, j = c & 7;
    hAbf[(size_t)(((p * 4 + q) * 64) + kg * 16 + r) * 8 + j] = f2bf(s);
}

// ---- attn mask
__global__ void k_mask(const float* __restrict__ ef, int* __restrict__ mask) {
    int e = blockIdx.x * blockDim.x + threadIdx.x;
    int m = 0;
#pragma unroll
    for (int k = 0; k < EFEAT; ++k) m |= (ef[e * EFEAT + k] != 0.f);
    mask[e] = m;
}

// ------------- K=32 swizzled GEMM: C[M][NC] = bf16(A_sw @ B_sw) -------------
// block 256 = 4 waves; wave = 64 rows (4 panels) x 64 cols (4 panels); block = 256 rows.
__global__ __launch_bounds__(256) void k_gemm32(const ushort_t* __restrict__ A_sw,
                                                const ushort_t* __restrict__ B_sw,
                                                ushort_t* __restrict__ C, int NC) {
    __shared__ ushort_t lds[4][64][64];   // 32 KB
    const int tid = threadIdx.x;
    const int l = tid & 63;
    const int w = tid >> 6;
    const int mpb = blockIdx.y * 16 + w * 4;
    const int cpb = blockIdx.x * 4;

    bf16x8 a[4], b[4];
#pragma unroll
    for (int mi = 0; mi < 4; ++mi)
        a[mi] = *(const bf16x8*)(A_sw + (size_t)((mpb + mi) * 64 + l) * 8);
#pragma unroll
    for (int ct = 0; ct < 4; ++ct)
        b[ct] = *(const bf16x8*)(B_sw + (size_t)((cpb + ct) * 64 + l) * 8);

    const int rb = (l >> 4) << 2, lc = l & 15;
#pragma unroll
    for (int mi = 0; mi < 4; ++mi)
#pragma unroll
        for (int ct = 0; ct < 4; ++ct) {
            f32x4 c = {0.f, 0.f, 0.f, 0.f};
            c = __builtin_amdgcn_mfma_f32_16x16x32_bf16(a[mi], b[ct], c, 0, 0, 0);
#pragma unroll
            for (int r = 0; r < 4; ++r)
                lds[w][mi * 16 + rb + r][ct * 16 + lc] = f2bf(c[r]);
        }
    __syncthreads();
#pragma unroll
    for (int i = 0; i < 8; ++i) {
        int ch = (i << 6) + l;
        int row = ch >> 3, co = (ch & 7) << 3;
        int grow = blockIdx.y * 256 + w * 64 + row;
        size_t gidx = (size_t)grow * NC + blockIdx.x * 64 + co;
        *(uint4*)(C + gidx) = *(const uint4*)(&lds[w][row][co]);
    }
}

// ------------- K=128 swizzled GEMM: C = bf16(A_sw @ B_sw + Cadd) -------------
// block 256 = 4 waves; wave = 32 rows (2 panels) x 64 cols; block = 128 rows.
__global__ __launch_bounds__(256) void k_gemm128(const ushort_t* __restrict__ A_sw,
                                                 const ushort_t* __restrict__ B_sw,
                                                 const ushort_t* __restrict__ Cadd,
                                                 ushort_t* __restrict__ C, int NC) {
    __shared__ ushort_t lds[4][32][64];   // 16 KB
    const int tid = threadIdx.x;
    const int l = tid & 63;
    const int w = tid >> 6;
    const int mpb = blockIdx.y * 8 + w * 2;
    const int cpb = blockIdx.x * 4;

    bf16x8 a[2][4], b[4][4];
#pragma unroll
    for (int mi = 0; mi < 2; ++mi)
#pragma unroll
        for (int q = 0; q < 4; ++q)
            a[mi][q] = *(const bf16x8*)(A_sw + (size_t)(((mpb + mi) * 4 + q) * 64 + l) * 8);
#pragma unroll
    for (int ct = 0; ct < 4; ++ct)
#pragma unroll
        for (int q = 0; q < 4; ++q)
            b[ct][q] = *(const bf16x8*)(B_sw + (size_t)(((cpb + ct) * 4 + q) * 64 + l) * 8);

    const int rb = (l >> 4) << 2, lc = l & 15;
#pragma unroll
    for (int mi = 0; mi < 2; ++mi)
#pragma unroll
        for (int ct = 0; ct < 4; ++ct) {
            f32x4 c = {0.f, 0.f, 0.f, 0.f};
#pragma unroll
            for (int q = 0; q < 4; ++q)
                c = __builtin_amdgcn_mfma_f32_16x16x32_bf16(a[mi][q], b[ct][q], c, 0, 0, 0);
#pragma unroll
            for (int r = 0; r < 4; ++r)
                lds[w][mi * 16 + rb + r][ct * 16 + lc] = f2bf(c[r]);
        }
    __syncthreads();
#pragma unroll
    for (int i = 0; i < 4; ++i) {
        int ch = (i << 6) + l;
        int row = ch >> 3, co = (ch & 7) << 3;
        int grow = blockIdx.y * 128 + w * 32 + row;
        size_t gidx = (size_t)grow * NC + blockIdx.x * 64 + co;
        uint4 sv = *(const uint4*)(&lds[w][row][co]);
        uint4 av = *(const uint4*)(Cadd + gidx);
        sv.x = addpack(sv.x, av.x);
        sv.y = addpack(sv.y, av.y);
        sv.z = addpack(sv.z, av.z);
        sv.w = addpack(sv.w, av.w);
        *(uint4*)(C + gidx) = sv;
    }
}

// ---------------- CSR build ----------------
__global__ void k_zero(int* p) { p[blockIdx.x * blockDim.x + threadIdx.x] = 0; }
__global__ void k_count(const int* __restrict__ src, int* __restrict__ deg) {
    int e = blockIdx.x * blockDim.x + threadIdx.x;
    atomicAdd(&deg[src[e]], 1);
}
__global__ __launch_bounds__(1024) void k_scan(const int* __restrict__ deg,
                                               int* __restrict__ offs, int* __restrict__ cursor) {
    __shared__ int sm[1024];
    int t = threadIdx.x;
    int d0 = deg[t * 4], d1 = deg[t * 4 + 1], d2 = deg[t * 4 + 2], d3 = deg[t * 4 + 3];
    int s = d0 + d1 + d2 + d3;
    sm[t] = s; __syncthreads();
    for (int o = 1; o < 1024; o <<= 1) {
        int v = (t >= o) ? sm[t - o] : 0;
        __syncthreads();
        sm[t] += v;
        __syncthreads();
    }
    int run = sm[t] - s;
    offs[t * 4] = run;     cursor[t * 4] = run;     run += d0;
    offs[t * 4 + 1] = run; cursor[t * 4 + 1] = run; run += d1;
    offs[t * 4 + 2] = run; cursor[t * 4 + 2] = run; run += d2;
    offs[t * 4 + 3] = run; cursor[t * 4 + 3] = run;
    if (t == 1023) offs[4096] = run + d3;
}
__global__ void k_fill(const int* __restrict__ src, int* __restrict__ cursor, int* __restrict__ eids) {
    int e = blockIdx.x * blockDim.x + threadIdx.x;
    int pos = atomicAdd(&cursor[src[e]], 1);
    eids[pos] = e;
}

// ------ fused edge pass (one wave per node), depth-1 prefetch, swizzled bf16 h output ------
__global__ __launch_bounds__(256) void k_edge(const ushort_t* __restrict__ T,    // [N][1536] bf16
                                              const ushort_t* __restrict__ eam,  // [E][1024] bf16
                                              const int* __restrict__ tgt,
                                              const int* __restrict__ offs,
                                              const int* __restrict__ eids,
                                              const int* __restrict__ mask,
                                              const float* __restrict__ a_kern,
                                              const int* __restrict__ n_states,
                                              const float* __restrict__ h_old,
                                              float* __restrict__ h_new,
                                              ushort_t* __restrict__ h_new_bf, int iter) {
    const int n = (blockIdx.x << 2) + (threadIdx.x >> 6);
    const int lane = threadIdx.x & 63;
    const int c0 = lane << 3;
    const int e0 = offs[n], e1 = offs[n + 1];

    float ak[8];
    {
        const float4* p = reinterpret_cast<const float4*>(a_kern + ((lane & 15) << 3));
        float4 a0 = p[0], a1 = p[1];
        ak[0] = a0.x; ak[1] = a0.y; ak[2] = a0.z; ak[3] = a0.w;
        ak[4] = a1.x; ak[5] = a1.y; ak[6] = a1.z; ak[7] = a1.w;
    }
    float asrc[8];
    load8bf(T + (size_t)n * TVAR + c0, asrc);

    float m = -INFINITY, s = 0.f;
    float acc[8] = {0, 0, 0, 0, 0, 0, 0, 0};

    int mk_n = 0;
    uint4 va_n, vt_n, vm_n, vtm_n;
    if (e0 < e1) {
        int e = eids[e0]; int t = tgt[e]; mk_n = mask[e];
        va_n  = *(const uint4*)(eam + (size_t)e * 1024 + c0);
        vt_n  = *(const uint4*)(T + (size_t)t * TVAR + 512 + c0);
        vm_n  = *(const uint4*)(eam + (size_t)e * 1024 + 512 + c0);
        vtm_n = *(const uint4*)(T + (size_t)t * TVAR + 1024 + c0);
    }
    for (int q = e0; q < e1; ++q) {
        uint4 va = va_n, vt = vt_n, vm = vm_n, vtm = vtm_n;
        int mk = mk_n;
        int q2 = q + 1;
        if (q2 < e1) {
            int e = eids[q2]; int t = tgt[e]; mk_n = mask[e];
            va_n  = *(const uint4*)(eam + (size_t)e * 1024 + c0);
            vt_n  = *(const uint4*)(T + (size_t)t * TVAR + 512 + c0);
            vm_n  = *(const uint4*)(eam + (size_t)e * 1024 + 512 + c0);
            vtm_n = *(const uint4*)(T + (size_t)t * TVAR + 1024 + c0);
        }
        float ea[8], tt[8], em[8], tm[8];
        unpack8(va, ea); unpack8(vt, tt); unpack8(vm, em); unpack8(vtm, tm);
        float p = 0.f;
#pragma unroll
        for (int j = 0; j < 8; ++j) {
            float v = asrc[j] + ea[j] + tt[j];
            v = (v > 0.f) ? v : 0.2f * v;          // leaky_relu 0.2
            p = fmaf(v, ak[j], p);
        }
        p += __shfl_xor(p, 1);
        p += __shfl_xor(p, 2);
        p += __shfl_xor(p, 4);
        p += __shfl_xor(p, 8);                     // per-head logit (16-lane group)
        p = mk ? p : -INFINITY;
        float mn = fmaxf(m, p);
        bool live = (mn != -INFINITY);
        float wgt = live ? __expf(p - mn) : 0.f;
        float sc  = live ? __expf(m - mn) : 0.f;
        s = s * sc + wgt;
#pragma unroll
        for (int j = 0; j < 8; ++j) acc[j] = acc[j] * sc + wgt * (em[j] + tm[j]);
        m = mn;
    }
    if (e1 > e0 && m == -INFINITY) {
        s = (float)(e1 - e0);
        for (int q = e0; q < e1; ++q) {
            int e = eids[q]; int t = tgt[e];
            float em[8], tm[8];
            load8bf(eam + (size_t)e * 1024 + 512 + c0, em);
            load8bf(T + (size_t)t * TVAR + 1024 + c0, tm);
#pragma unroll
            for (int j = 0; j < 8; ++j) acc[j] += em[j] + tm[j];
        }
    }
    float inv = (e1 > e0) ? (1.f / s) : 0.f;
    float r[8];
#pragma unroll
    for (int j = 0; j < 8; ++j) {
        float v = acc[j] * inv;
        v += __shfl_xor(v, 16);
        v += __shfl_xor(v, 32);
        r[j] = v;
    }
    bool upd = iter < n_states[n];
    if (lane < 16) {
        float out[8];
#pragma unroll
        for (int j = 0; j < 8; ++j)
            out[j] = upd ? tanhf(r[j]) : h_old[(size_t)n * HIDD + c0 + j];
        float4* ph = reinterpret_cast<float4*>(h_new + (size_t)n * HIDD + c0);
        float4 o0, o1;
        o0.x = out[0]; o0.y = out[1]; o0.z = out[2]; o0.w = out[3];
        o1.x = out[4]; o1.y = out[5]; o1.z = out[6]; o1.w = out[7];
        ph[0] = o0; ph[1] = o1;
        // swizzled bf16 store: p,r from node; q,kg from lane
        int p = n >> 4, rr = n & 15, q = lane >> 2, kg = lane & 3;
        *(uint4*)(h_new_bf + (size_t)(((p * 4 + q) * 64) + kg * 16 + rr) * 8) = pack8(out);
    }
}

// ---------------- out = h[cs] @ W_g ----------------
__global__ void k_out(const float* __restrict__ h, const int* __restrict__ cs,
                      const float* __restrict__ Wg, float* __restrict__ out) {
    int idx = blockIdx.x * blockDim.x + threadIdx.x;   // B*ENC
    int b = idx >> 6, c = idx & 63;
    int n = cs[b];
    float s = 0.f;
#pragma unroll
    for (int k = 0; k < HIDD; ++k) s += h[(size_t)n * HIDD + k] * Wg[k * ENCD + c];
    out[idx] = s;
}

extern "C" void kernel_launch(void* const* d_in, const int* in_sizes, int n_in,
                              void* d_out, int out_size, void* d_ws, size_t ws_size,
                              hipStream_t stream) {
    const float* nf  = (const float*)d_in[0];
    const float* ef  = (const float*)d_in[1];
    const int* eidx  = (const int*)d_in[2];
    const int* cs    = (const int*)d_in[3];
    const int* nst   = (const int*)d_in[4];
    const float* Wh  = (const float*)d_in[5];
    const float* We  = (const float*)d_in[6];
    const float* Wa  = (const float*)d_in[7];
    const float* Wm  = (const float*)d_in[8];
    const float* akn = (const float*)d_in[9];
    const float* Wg  = (const float*)d_in[10];
    const int* src = eidx;
    const int* tgt = eidx + N_EDGES;

    char* w = (char*)d_ws;
    size_t off = 0;
    auto alloc = [&](size_t bytes) -> void* {
        void* p = w + off;
        off = (off + bytes + 255) & ~(size_t)255;
        return p;
    };
    float* hA        = (float*)alloc((size_t)N_NODES * HIDD * 4);
    float* hB        = (float*)alloc((size_t)N_NODES * HIDD * 4);
    ushort_t* hAbf   = (ushort_t*)alloc((size_t)N_NODES * HIDD * 2);
    ushort_t* hBbf   = (ushort_t*)alloc((size_t)N_NODES * HIDD * 2);
    int* mask        = (int*)alloc((size_t)N_EDGES * 4);
    ushort_t* eam    = (ushort_t*)alloc((size_t)N_EDGES * 1024 * 2);   // 64 MB
    ushort_t* Tfix   = (ushort_t*)alloc((size_t)N_NODES * TVAR * 2);   // 12 MB
    ushort_t* Tcur   = (ushort_t*)alloc((size_t)N_NODES * TVAR * 2);   // 12 MB
    ushort_t* Wcomb  = (ushort_t*)alloc((size_t)64 * 64 * 8 * 2);      // 64 KB
    ushort_t* WfixC  = (ushort_t*)alloc((size_t)96 * 64 * 8 * 2);      // 96 KB
    ushort_t* WvarSw = (ushort_t*)alloc((size_t)96 * 4 * 64 * 8 * 2);  // 384 KB
    ushort_t* efp    = (ushort_t*)alloc((size_t)2048 * 64 * 8 * 2);    // 2 MB
    ushort_t* nfp    = (ushort_t*)alloc((size_t)256 * 64 * 8 * 2);     // 256 KB
    int* deg         = (int*)alloc((size_t)N_NODES * 4);
    int* offs        = (int*)alloc((size_t)(N_NODES + 1) * 4);
    int* cursor      = (int*)alloc((size_t)N_NODES * 4);
    int* eids        = (int*)alloc((size_t)N_EDGES * 4);
    (void)ws_size; (void)in_sizes; (void)n_in; (void)out_size;  // ~95 MB used

    k_comp_eam<<<64, 256, 0, stream>>>(We, Wa, Wm, Wcomb);
    k_comp_fix<<<96, 256, 0, stream>>>(Wh, Wa, Wm, WfixC);
    k_pack_var<<<96, 256, 0, stream>>>(Wa, Wm, WvarSw);
    k_prep_ef<<<512, 256, 0, stream>>>(ef, efp);
    k_prep_nf<<<64, 256, 0, stream>>>(nf, nfp);
    k_h0<<<(N_NODES * HIDD) / 256, 256, 0, stream>>>(nf, Wh, hA, hAbf);
    k_mask<<<N_EDGES / 256, 256, 0, stream>>>(ef, mask);

    // eam[E][1024] = efp @ Wcomb (K=16 padded to 32)
    k_gemm32<<<dim3(1024 / 64, N_EDGES / 256), 256, 0, stream>>>(efp, Wcomb, eam, 1024);
    // Tfix[N][1536] = nfp @ WfixC (K=32)
    k_gemm32<<<dim3(TVAR / 64, N_NODES / 256), 256, 0, stream>>>(nfp, WfixC, Tfix, TVAR);

    k_zero<<<N_NODES / 256, 256, 0, stream>>>(deg);
    k_count<<<N_EDGES / 256, 256, 0, stream>>>(src, deg);
    k_scan<<<1, 1024, 0, stream>>>(deg, offs, cursor);
    k_fill<<<N_EDGES / 256, 256, 0, stream>>>(src, cursor, eids);

    float* hcur = hA; float* hnext = hB;
    ushort_t* hcbf = hAbf; ushort_t* hnbf = hBbf;
    for (int i = 0; i < MAXS; ++i) {
        k_gemm128<<<dim3(TVAR / 64, N_NODES / 128), 256, 0, stream>>>(hcbf, WvarSw, Tfix, Tcur, TVAR);
        k_edge<<<N_NODES / 4, 256, 0, stream>>>(Tcur, eam, tgt, offs, eids, mask, akn, nst,
                                                hcur, hnext, hnbf, i);
        float* tmp = hcur; hcur = hnext; hnext = tmp;
        ushort_t* tb = hcbf; hcbf = hnbf; hnbf = tb;
    }
    k_out<<<(BATCH * ENCD) / 256, 256, 0, stream>>>(hcur, cs, Wg, (float*)d_out);
}

// Round 12
// 450.462 us; speedup vs baseline: 1.7868x; 1.1047x over previous
//
#include <hip/hip_runtime.h>
#include <hip/hip_bf16.h>

// Problem constants (fixed by the reference)
#define N_NODES 4096
#define N_EDGES 32768
#define BATCH   1024
#define NFEAT   32
#define EFEAT   16
#define ENCD    64
#define HIDD    128
#define HEADS   4
#define HID4    512
#define MAXS    10
#define TVAR    1536   // 3*HID4: [src-attn | tgt-attn | tgt-msg] node tables

typedef unsigned short ushort_t;
typedef __bf16 bf16x8 __attribute__((ext_vector_type(8)));
typedef float f32x4 __attribute__((ext_vector_type(4)));

static __device__ __forceinline__ float bfbits2f(unsigned int hi16) {
    return __uint_as_float(hi16);
}
static __device__ __forceinline__ void unpack8(uint4 v, float* f) {
    f[0] = bfbits2f(v.x << 16); f[1] = bfbits2f(v.x & 0xffff0000u);
    f[2] = bfbits2f(v.y << 16); f[3] = bfbits2f(v.y & 0xffff0000u);
    f[4] = bfbits2f(v.z << 16); f[5] = bfbits2f(v.z & 0xffff0000u);
    f[6] = bfbits2f(v.w << 16); f[7] = bfbits2f(v.w & 0xffff0000u);
}
static __device__ __forceinline__ void load8bf(const ushort_t* p, float* f) {
    unpack8(*reinterpret_cast<const uint4*>(p), f);
}
static __device__ __forceinline__ unsigned short f2bf(float x) {
    __hip_bfloat16 h = __float2bfloat16(x);
    return *reinterpret_cast<unsigned short*>(&h);
}
static __device__ __forceinline__ unsigned addpack(unsigned s, unsigned a) {
    float s0 = bfbits2f(s << 16), s1 = bfbits2f(s & 0xffff0000u);
    float a0 = bfbits2f(a << 16), a1 = bfbits2f(a & 0xffff0000u);
    unsigned r0 = f2bf(s0 + a0), r1 = f2bf(s1 + a1);
    return r0 | (r1 << 16);
}
static __device__ __forceinline__ uint4 pack8(const float* f) {
    uint4 u;
    u.x = (unsigned)f2bf(f[0]) | ((unsigned)f2bf(f[1]) << 16);
    u.y = (unsigned)f2bf(f[2]) | ((unsigned)f2bf(f[3]) << 16);
    u.z = (unsigned)f2bf(f[4]) | ((unsigned)f2bf(f[5]) << 16);
    u.w = (unsigned)f2bf(f[6]) | ((unsigned)f2bf(f[7]) << 16);
    return u;
}

// Fragment-swizzled layout for a [rows][K] bf16 operand of mfma_f32_16x16x32_bf16:
//   element (row, k) lives at ((panel*NQ + q)*64 + kgrp*16 + r)*8 + j
//   panel=row>>4, r=row&15, q=k>>5, kgrp=(k>>3)&3, j=k&7
// A wave's fragment load is then base + lane*16B  ->  one contiguous 1KB transaction.

// ---- Wcomb_sw = swizzle(pad32(We @ Weam)); one block per 16-col panel, LDS-staged.
__global__ __launch_bounds__(256) void k_comp_eam(const float* __restrict__ We,
                                                  const float* __restrict__ Wa,
                                                  const float* __restrict__ Wm,
                                                  ushort_t* __restrict__ out) {
    __shared__ float w_lds[128][17];
    const int t = threadIdx.x;
    const int p = blockIdx.x;          // 64 panels
    const int cl = t & 15, kbase = t >> 4;
    const int c = p * 16 + cl;
#pragma unroll
    for (int i = 0; i < 8; ++i) {      // 8 independent coalesced loads
        int kk = kbase + i * 16;
        w_lds[kk][cl] = (c < 512) ? Wa[(256 + kk) * HID4 + c] : Wm[kk * HID4 + (c - 512)];
    }
    __syncthreads();
    const int k = t >> 4;              // 0..15 (output K row)
    float s = 0.f;
    for (int kk = 0; kk < 128; ++kk)
        s = fmaf(We[k * 128 + kk], w_lds[kk][cl], s);
    int l = ((k >> 3) << 4) + cl, j = k & 7;
    out[((size_t)(p * 64 + l)) * 8 + j] = f2bf(s);
    if (t < 32) {                      // zero-pad k in [16,32): lanes 32..63
        uint4 z = {0, 0, 0, 0};
        *(uint4*)(out + ((size_t)(p * 64 + 32 + t)) * 8) = z;
    }
}

// ---- WfixC_sw = swizzle(Wh @ Wfix), K=32 exact; one block per 16-col panel.
__global__ __launch_bounds__(256) void k_comp_fix(const float* __restrict__ Wh,
                                                  const float* __restrict__ Wa,
                                                  const float* __restrict__ Wm,
                                                  ushort_t* __restrict__ out) {
    __shared__ float w_lds[128][17];
    const int t = threadIdx.x;
    const int p = blockIdx.x;          // 96 panels
    const int cl = t & 15, kbase = t >> 4;
    const int c = p * 16 + cl;
#pragma unroll
    for (int i = 0; i < 8; ++i) {
        int kk = kbase + i * 16;
        w_lds[kk][cl] = (c < 512) ? Wa[(128 + kk) * HID4 + c]
                      : (c < 1024) ? Wa[(512 + kk) * HID4 + (c - 512)]
                                   : Wm[(256 + kk) * HID4 + (c - 1024)];
    }
    __syncthreads();
    const int k1 = t >> 4, k2 = k1 + 16;
    float s1 = 0.f, s2 = 0.f;
    for (int kk = 0; kk < 128; ++kk) {
        float wv = w_lds[kk][cl];
        s1 = fmaf(Wh[k1 * 128 + kk], wv, s1);
        s2 = fmaf(Wh[k2 * 128 + kk], wv, s2);
    }
    int l1 = ((k1 >> 3) << 4) + cl, j1 = k1 & 7;
    int l2 = ((k2 >> 3) << 4) + cl, j2 = k2 & 7;
    out[((size_t)(p * 64 + l1)) * 8 + j1] = f2bf(s1);
    out[((size_t)(p * 64 + l2)) * 8 + j2] = f2bf(s2);
}

// ---- Wvar_sw = swizzle(Wvar[128][1536])
__global__ void k_pack_var(const float* __restrict__ Wa, const float* __restrict__ Wm,
                           ushort_t* __restrict__ out) {
    int idx = blockIdx.x * blockDim.x + threadIdx.x;   // 96 panels * 4 q * 64 lanes
    int p = idx >> 8, rem = idx & 255;
    int q = rem >> 6, l = rem & 63;
    int c = p * 16 + (l & 15);
    int k0 = q * 32 + ((l >> 4) << 3);
    float v[8];
#pragma unroll
    for (int j = 0; j < 8; ++j) {
        int k = k0 + j;
        v[j] = (c < 512) ? Wa[k * HID4 + c]
             : (c < 1024) ? Wa[(384 + k) * HID4 + (c - 512)]
                          : Wm[(128 + k) * HID4 + (c - 1024)];
    }
    *(uint4*)(out + (size_t)idx * 8) = pack8(v);
}

// ---- efp_sw = swizzle(pad32(ef[E][16]))
__global__ void k_prep_ef(const float* __restrict__ ef, ushort_t* __restrict__ out) {
    int idx = blockIdx.x * blockDim.x + threadIdx.x;   // 2048 panels * 64 lanes
    int p = idx >> 6, l = idx & 63;
    int e = p * 16 + (l & 15);
    int k0 = (l >> 4) << 3;
    float v[8];
#pragma unroll
    for (int j = 0; j < 8; ++j) {
        int k = k0 + j;
        v[j] = (k < 16) ? ef[e * EFEAT + k] : 0.f;
    }
    *(uint4*)(out + (size_t)idx * 8) = pack8(v);
}

// ---- nfp_sw = swizzle(nf[N][32]), K=32 exact
__global__ void k_prep_nf(const float* __restrict__ nf, ushort_t* __restrict__ out) {
    int idx = blockIdx.x * blockDim.x + threadIdx.x;   // 256 panels * 64 lanes
    int p = idx >> 6, l = idx & 63;
    int n = p * 16 + (l & 15);
    int k0 = (l >> 4) << 3;
    float v[8];
#pragma unroll
    for (int j = 0; j < 8; ++j) v[j] = nf[n * NFEAT + k0 + j];
    *(uint4*)(out + (size_t)idx * 8) = pack8(v);
}

// ---- h0 = nf @ W_h : hA f32 (natural) + hAbf (swizzled)
__global__ void k_h0(const float* __restrict__ nf, const float* __restrict__ Wh,
                     float* __restrict__ hA, ushort_t* __restrict__ hAbf) {
    int idx = blockIdx.x * blockDim.x + threadIdx.x;   // N*HID
    int n = idx >> 7, c = idx & 127;
    float s = 0.f;
#pragma unroll
    for (int k = 0; k < NFEAT; ++k) s += nf[n * NFEAT + k] * Wh[k * HIDD + c];
    hA[idx] = s;
    int p = n >> 4, r = n & 15, q = c >> 5, kg = (c >> 3) & 3, j = c & 7;
    hAbf[(size_t)(((p * 4 + q) * 64) + kg * 16 + r) * 8 + j] = f2bf(s);
}

// ---- attn mask
__global__ void k_mask(const float* __restrict__ ef, int* __restrict__ mask) {
    int e = blockIdx.x * blockDim.x + threadIdx.x;
    int m = 0;
#pragma unroll
    for (int k = 0; k < EFEAT; ++k) m |= (ef[e * EFEAT + k] != 0.f);
    mask[e] = m;
}

// ------------- K=32 swizzled GEMM: C[M][NC] = bf16(A_sw @ B_sw) -------------
// block 256 = 4 waves; wave = 64 rows (4 panels) x 64 cols (4 panels); block = 256 rows.
__global__ __launch_bounds__(256) void k_gemm32(const ushort_t* __restrict__ A_sw,
                                                const ushort_t* __restrict__ B_sw,
                                                ushort_t* __restrict__ C, int NC) {
    __shared__ ushort_t lds[4][64][64];   // 32 KB
    const int tid = threadIdx.x;
    const int l = tid & 63;
    const int w = tid >> 6;
    const int mpb = blockIdx.y * 16 + w * 4;
    const int cpb = blockIdx.x * 4;

    bf16x8 a[4], b[4];
#pragma unroll
    for (int mi = 0; mi < 4; ++mi)
        a[mi] = *(const bf16x8*)(A_sw + (size_t)((mpb + mi) * 64 + l) * 8);
#pragma unroll
    for (int ct = 0; ct < 4; ++ct)
        b[ct] = *(const bf16x8*)(B_sw + (size_t)((cpb + ct) * 64 + l) * 8);

    const int rb = (l >> 4) << 2, lc = l & 15;
#pragma unroll
    for (int mi = 0; mi < 4; ++mi)
#pragma unroll
        for (int ct = 0; ct < 4; ++ct) {
            f32x4 c = {0.f, 0.f, 0.f, 0.f};
            c = __builtin_amdgcn_mfma_f32_16x16x32_bf16(a[mi], b[ct], c, 0, 0, 0);
#pragma unroll
            for (int r = 0; r < 4; ++r)
                lds[w][mi * 16 + rb + r][ct * 16 + lc] = f2bf(c[r]);
        }
    __syncthreads();
#pragma unroll
    for (int i = 0; i < 8; ++i) {
        int ch = (i << 6) + l;
        int row = ch >> 3, co = (ch & 7) << 3;
        int grow = blockIdx.y * 256 + w * 64 + row;
        size_t gidx = (size_t)grow * NC + blockIdx.x * 64 + co;
        *(uint4*)(C + gidx) = *(const uint4*)(&lds[w][row][co]);
    }
}

// ------------- K=128 swizzled GEMM: C = bf16(A_sw @ B_sw + Cadd) -------------
// block 256 = 4 waves; wave = 32 rows (2 panels) x 64 cols; block = 128 rows.
__global__ __launch_bounds__(256) void k_gemm128(const ushort_t* __restrict__ A_sw,
                                                 const ushort_t* __restrict__ B_sw,
                                                 const ushort_t* __restrict__ Cadd,
                                                 ushort_t* __restrict__ C, int NC) {
    __shared__ ushort_t lds[4][32][64];   // 16 KB
    const int tid = threadIdx.x;
    const int l = tid & 63;
    const int w = tid >> 6;
    const int mpb = blockIdx.y * 8 + w * 2;
    const int cpb = blockIdx.x * 4;

    bf16x8 a[2][4], b[4][4];
#pragma unroll
    for (int mi = 0; mi < 2; ++mi)
#pragma unroll
        for (int q = 0; q < 4; ++q)
            a[mi][q] = *(const bf16x8*)(A_sw + (size_t)(((mpb + mi) * 4 + q) * 64 + l) * 8);
#pragma unroll
    for (int ct = 0; ct < 4; ++ct)
#pragma unroll
        for (int q = 0; q < 4; ++q)
            b[ct][q] = *(const bf16x8*)(B_sw + (size_t)(((cpb + ct) * 4 + q) * 64 + l) * 8);

    const int rb = (l >> 4) << 2, lc = l & 15;
#pragma unroll
    for (int mi = 0; mi < 2; ++mi)
#pragma unroll
        for (int ct = 0; ct < 4; ++ct) {
            f32x4 c = {0.f, 0.f, 0.f, 0.f};
#pragma unroll
            for (int q = 0; q < 4; ++q)
                c = __builtin_amdgcn_mfma_f32_16x16x32_bf16(a[mi][q], b[ct][q], c, 0, 0, 0);
#pragma unroll
            for (int r = 0; r < 4; ++r)
                lds[w][mi * 16 + rb + r][ct * 16 + lc] = f2bf(c[r]);
        }
    __syncthreads();
#pragma unroll
    for (int i = 0; i < 4; ++i) {
        int ch = (i << 6) + l;
        int row = ch >> 3, co = (ch & 7) << 3;
        int grow = blockIdx.y * 128 + w * 32 + row;
        size_t gidx = (size_t)grow * NC + blockIdx.x * 64 + co;
        uint4 sv = *(const uint4*)(&lds[w][row][co]);
        uint4 av = *(const uint4*)(Cadd + gidx);
        sv.x = addpack(sv.x, av.x);
        sv.y = addpack(sv.y, av.y);
        sv.z = addpack(sv.z, av.z);
        sv.w = addpack(sv.w, av.w);
        *(uint4*)(C + gidx) = sv;
    }
}

// ---------------- CSR build ----------------
__global__ void k_zero(int* p) { p[blockIdx.x * blockDim.x + threadIdx.x] = 0; }
__global__ void k_count(const int* __restrict__ src, int* __restrict__ deg) {
    int e = blockIdx.x * blockDim.x + threadIdx.x;
    atomicAdd(&deg[src[e]], 1);
}
__global__ __launch_bounds__(1024) void k_scan(const int* __restrict__ deg,
                                               int* __restrict__ offs, int* __restrict__ cursor) {
    __shared__ int sm[1024];
    int t = threadIdx.x;
    int d0 = deg[t * 4], d1 = deg[t * 4 + 1], d2 = deg[t * 4 + 2], d3 = deg[t * 4 + 3];
    int s = d0 + d1 + d2 + d3;
    sm[t] = s; __syncthreads();
    for (int o = 1; o < 1024; o <<= 1) {
        int v = (t >= o) ? sm[t - o] : 0;
        __syncthreads();
        sm[t] += v;
        __syncthreads();
    }
    int run = sm[t] - s;
    offs[t * 4] = run;     cursor[t * 4] = run;     run += d0;
    offs[t * 4 + 1] = run; cursor[t * 4 + 1] = run; run += d1;
    offs[t * 4 + 2] = run; cursor[t * 4 + 2] = run; run += d2;
    offs[t * 4 + 3] = run; cursor[t * 4 + 3] = run;
    if (t == 1023) offs[4096] = run + d3;
}
__global__ void k_fill(const int* __restrict__ src, int* __restrict__ cursor, int* __restrict__ eids) {
    int e = blockIdx.x * blockDim.x + threadIdx.x;
    int pos = atomicAdd(&cursor[src[e]], 1);
    eids[pos] = e;
}

// ------ fused edge pass (one wave per node), depth-1 prefetch, swizzled bf16 h output ------
// Frozen-node early exit: iter >= n_states[n] -> h unchanged, skip edge loop entirely (exact).
__global__ __launch_bounds__(256) void k_edge(const ushort_t* __restrict__ T,    // [N][1536] bf16
                                              const ushort_t* __restrict__ eam,  // [E][1024] bf16
                                              const int* __restrict__ tgt,
                                              const int* __restrict__ offs,
                                              const int* __restrict__ eids,
                                              const int* __restrict__ mask,
                                              const float* __restrict__ a_kern,
                                              const int* __restrict__ n_states,
                                              const float* __restrict__ h_old,
                                              float* __restrict__ h_new,
                                              ushort_t* __restrict__ h_new_bf, int iter) {
    const int n = (blockIdx.x << 2) + (threadIdx.x >> 6);
    const int lane = threadIdx.x & 63;
    const int c0 = lane << 3;

    const bool upd = iter < n_states[n];
    if (!upd) {
        // frozen: h_new = h_old (copy + swizzled bf16 pack), no edge work
        if (lane < 16) {
            const float4* po = reinterpret_cast<const float4*>(h_old + (size_t)n * HIDD + c0);
            float4 o0 = po[0], o1 = po[1];
            float4* ph = reinterpret_cast<float4*>(h_new + (size_t)n * HIDD + c0);
            ph[0] = o0; ph[1] = o1;
            float out[8] = {o0.x, o0.y, o0.z, o0.w, o1.x, o1.y, o1.z, o1.w};
            int p = n >> 4, rr = n & 15, q = lane >> 2, kg = lane & 3;
            *(uint4*)(h_new_bf + (size_t)(((p * 4 + q) * 64) + kg * 16 + rr) * 8) = pack8(out);
        }
        return;
    }

    const int e0 = offs[n], e1 = offs[n + 1];

    float ak[8];
    {
        const float4* p = reinterpret_cast<const float4*>(a_kern + ((lane & 15) << 3));
        float4 a0 = p[0], a1 = p[1];
        ak[0] = a0.x; ak[1] = a0.y; ak[2] = a0.z; ak[3] = a0.w;
        ak[4] = a1.x; ak[5] = a1.y; ak[6] = a1.z; ak[7] = a1.w;
    }
    float asrc[8];
    load8bf(T + (size_t)n * TVAR + c0, asrc);

    float m = -INFINITY, s = 0.f;
    float acc[8] = {0, 0, 0, 0, 0, 0, 0, 0};

    int mk_n = 0;
    uint4 va_n, vt_n, vm_n, vtm_n;
    if (e0 < e1) {
        int e = eids[e0]; int t = tgt[e]; mk_n = mask[e];
        va_n  = *(const uint4*)(eam + (size_t)e * 1024 + c0);
        vt_n  = *(const uint4*)(T + (size_t)t * TVAR + 512 + c0);
        vm_n  = *(const uint4*)(eam + (size_t)e * 1024 + 512 + c0);
        vtm_n = *(const uint4*)(T + (size_t)t * TVAR + 1024 + c0);
    }
    for (int q = e0; q < e1; ++q) {
        uint4 va = va_n, vt = vt_n, vm = vm_n, vtm = vtm_n;
        int mk = mk_n;
        int q2 = q + 1;
        if (q2 < e1) {
            int e = eids[q2]; int t = tgt[e]; mk_n = mask[e];
            va_n  = *(const uint4*)(eam + (size_t)e * 1024 + c0);
            vt_n  = *(const uint4*)(T + (size_t)t * TVAR + 512 + c0);
            vm_n  = *(const uint4*)(eam + (size_t)e * 1024 + 512 + c0);
            vtm_n = *(const uint4*)(T + (size_t)t * TVAR + 1024 + c0);
        }
        float ea[8], tt[8], em[8], tm[8];
        unpack8(va, ea); unpack8(vt, tt); unpack8(vm, em); unpack8(vtm, tm);
        float p = 0.f;
#pragma unroll
        for (int j = 0; j < 8; ++j) {
            float v = asrc[j] + ea[j] + tt[j];
            v = (v > 0.f) ? v : 0.2f * v;          // leaky_relu 0.2
            p = fmaf(v, ak[j], p);
        }
        p += __shfl_xor(p, 1);
        p += __shfl_xor(p, 2);
        p += __shfl_xor(p, 4);
        p += __shfl_xor(p, 8);                     // per-head logit (16-lane group)
        p = mk ? p : -INFINITY;
        float mn = fmaxf(m, p);
        bool live = (mn != -INFINITY);
        float wgt = live ? __expf(p - mn) : 0.f;
        float sc  = live ? __expf(m - mn) : 0.f;
        s = s * sc + wgt;
#pragma unroll
        for (int j = 0; j < 8; ++j) acc[j] = acc[j] * sc + wgt * (em[j] + tm[j]);
        m = mn;
    }
    if (e1 > e0 && m == -INFINITY) {
        s = (float)(e1 - e0);
        for (int q = e0; q < e1; ++q) {
            int e = eids[q]; int t = tgt[e];
            float em[8], tm[8];
            load8bf(eam + (size_t)e * 1024 + 512 + c0, em);
            load8bf(T + (size_t)t * TVAR + 1024 + c0, tm);
#pragma unroll
            for (int j = 0; j < 8; ++j) acc[j] += em[j] + tm[j];
        }
    }
    float inv = (e1 > e0) ? (1.f / s) : 0.f;
    float r[8];
#pragma unroll
    for (int j = 0; j < 8; ++j) {
        float v = acc[j] * inv;
        v += __shfl_xor(v, 16);
        v += __shfl_xor(v, 32);
        r[j] = v;
    }
    if (lane < 16) {
        float out[8];
#pragma unroll
        for (int j = 0; j < 8; ++j) out[j] = tanhf(r[j]);
        float4* ph = reinterpret_cast<float4*>(h_new + (size_t)n * HIDD + c0);
        float4 o0, o1;
        o0.x = out[0]; o0.y = out[1]; o0.z = out[2]; o0.w = out[3];
        o1.x = out[4]; o1.y = out[5]; o1.z = out[6]; o1.w = out[7];
        ph[0] = o0; ph[1] = o1;
        // swizzled bf16 store: p,r from node; q,kg from lane
        int p = n >> 4, rr = n & 15, q = lane >> 2, kg = lane & 3;
        *(uint4*)(h_new_bf + (size_t)(((p * 4 + q) * 64) + kg * 16 + rr) * 8) = pack8(out);
    }
}

// ---------------- out = h[cs] @ W_g ----------------
__global__ void k_out(const float* __restrict__ h, const int* __restrict__ cs,
                      const float* __restrict__ Wg, float* __restrict__ out) {
    int idx = blockIdx.x * blockDim.x + threadIdx.x;   // B*ENC
    int b = idx >> 6, c = idx & 63;
    int n = cs[b];
    float s = 0.f;
#pragma unroll
    for (int k = 0; k < HIDD; ++k) s += h[(size_t)n * HIDD + k] * Wg[k * ENCD + c];
    out[idx] = s;
}

extern "C" void kernel_launch(void* const* d_in, const int* in_sizes, int n_in,
                              void* d_out, int out_size, void* d_ws, size_t ws_size,
                              hipStream_t stream) {
    const float* nf  = (const float*)d_in[0];
    const float* ef  = (const float*)d_in[1];
    const int* eidx  = (const int*)d_in[2];
    const int* cs    = (const int*)d_in[3];
    const int* nst   = (const int*)d_in[4];
    const float* Wh  = (const float*)d_in[5];
    const float* We  = (const float*)d_in[6];
    const float* Wa  = (const float*)d_in[7];
    const float* Wm  = (const float*)d_in[8];
    const float* akn = (const float*)d_in[9];
    const float* Wg  = (const float*)d_in[10];
    const int* src = eidx;
    const int* tgt = eidx + N_EDGES;

    char* w = (char*)d_ws;
    size_t off = 0;
    auto alloc = [&](size_t bytes) -> void* {
        void* p = w + off;
        off = (off + bytes + 255) & ~(size_t)255;
        return p;
    };
    float* hA        = (float*)alloc((size_t)N_NODES * HIDD * 4);
    float* hB        = (float*)alloc((size_t)N_NODES * HIDD * 4);
    ushort_t* hAbf   = (ushort_t*)alloc((size_t)N_NODES * HIDD * 2);
    ushort_t* hBbf   = (ushort_t*)alloc((size_t)N_NODES * HIDD * 2);
    int* mask        = (int*)alloc((size_t)N_EDGES * 4);
    ushort_t* eam    = (ushort_t*)alloc((size_t)N_EDGES * 1024 * 2);   // 64 MB
    ushort_t* Tfix   = (ushort_t*)alloc((size_t)N_NODES * TVAR * 2);   // 12 MB
    ushort_t* Tcur   = (ushort_t*)alloc((size_t)N_NODES * TVAR * 2);   // 12 MB
    ushort_t* Wcomb  = (ushort_t*)alloc((size_t)64 * 64 * 8 * 2);      // 64 KB
    ushort_t* WfixC  = (ushort_t*)alloc((size_t)96 * 64 * 8 * 2);      // 96 KB
    ushort_t* WvarSw = (ushort_t*)alloc((size_t)96 * 4 * 64 * 8 * 2);  // 384 KB
    ushort_t* efp    = (ushort_t*)alloc((size_t)2048 * 64 * 8 * 2);    // 2 MB
    ushort_t* nfp    = (ushort_t*)alloc((size_t)256 * 64 * 8 * 2);     // 256 KB
    int* deg         = (int*)alloc((size_t)N_NODES * 4);
    int* offs        = (int*)alloc((size_t)(N_NODES + 1) * 4);
    int* cursor      = (int*)alloc((size_t)N_NODES * 4);
    int* eids        = (int*)alloc((size_t)N_EDGES * 4);
    (void)ws_size; (void)in_sizes; (void)n_in; (void)out_size;  // ~95 MB used

    k_comp_eam<<<64, 256, 0, stream>>>(We, Wa, Wm, Wcomb);
    k_comp_fix<<<96, 256, 0, stream>>>(Wh, Wa, Wm, WfixC);
    k_pack_var<<<96, 256, 0, stream>>>(Wa, Wm, WvarSw);
    k_prep_ef<<<512, 256, 0, stream>>>(ef, efp);
    k_prep_nf<<<64, 256, 0, stream>>>(nf, nfp);
    k_h0<<<(N_NODES * HIDD) / 256, 256, 0, stream>>>(nf, Wh, hA, hAbf);
    k_mask<<<N_EDGES / 256, 256, 0, stream>>>(ef, mask);

    // eam[E][1024] = efp @ Wcomb (K=16 padded to 32)
    k_gemm32<<<dim3(1024 / 64, N_EDGES / 256), 256, 0, stream>>>(efp, Wcomb, eam, 1024);
    // Tfix[N][1536] = nfp @ WfixC (K=32)
    k_gemm32<<<dim3(TVAR / 64, N_NODES / 256), 256, 0, stream>>>(nfp, WfixC, Tfix, TVAR);

    k_zero<<<N_NODES / 256, 256, 0, stream>>>(deg);
    k_count<<<N_EDGES / 256, 256, 0, stream>>>(src, deg);
    k_scan<<<1, 1024, 0, stream>>>(deg, offs, cursor);
    k_fill<<<N_EDGES / 256, 256, 0, stream>>>(src, cursor, eids);

    float* hcur = hA; float* hnext = hB;
    ushort_t* hcbf = hAbf; ushort_t* hnbf = hBbf;
    for (int i = 0; i < MAXS; ++i) {
        k_gemm128<<<dim3(TVAR / 64, N_NODES / 128), 256, 0, stream>>>(hcbf, WvarSw, Tfix, Tcur, TVAR);
        k_edge<<<N_NODES / 4, 256, 0, stream>>>(Tcur, eam, tgt, offs, eids, mask, akn, nst,
                                                hcur, hnext, hnbf, i);
        float* tmp = hcur; hcur = hnext; hnext = tmp;
        ushort_t* tb = hcbf; hcbf = hnbf; hnbf = tb;
    }
    k_out<<<(BATCH * ENCD) / 256, 256, 0, stream>>>(hcur, cs, Wg, (float*)d_out);
}

// Round 13
// 444.634 us; speedup vs baseline: 1.8103x; 1.0131x over previous
//
#include <hip/hip_runtime.h>
#include <hip/hip_bf16.h>

// Problem constants (fixed by the reference)
#define N_NODES 4096
#define N_EDGES 32768
#define BATCH   1024
#define NFEAT   32
#define EFEAT   16
#define ENCD    64
#define HIDD    128
#define HEADS   4
#define HID4    512
#define MAXS    10
#define TVAR    1536   // 3*HID4: [src-attn | tgt-attn | tgt-msg] node tables

typedef unsigned short ushort_t;
typedef __bf16 bf16x8 __attribute__((ext_vector_type(8)));
typedef float f32x4 __attribute__((ext_vector_type(4)));

static __device__ __forceinline__ float bfbits2f(unsigned int hi16) {
    return __uint_as_float(hi16);
}
static __device__ __forceinline__ void unpack8(uint4 v, float* f) {
    f[0] = bfbits2f(v.x << 16); f[1] = bfbits2f(v.x & 0xffff0000u);
    f[2] = bfbits2f(v.y << 16); f[3] = bfbits2f(v.y & 0xffff0000u);
    f[4] = bfbits2f(v.z << 16); f[5] = bfbits2f(v.z & 0xffff0000u);
    f[6] = bfbits2f(v.w << 16); f[7] = bfbits2f(v.w & 0xffff0000u);
}
static __device__ __forceinline__ void load8bf(const ushort_t* p, float* f) {
    unpack8(*reinterpret_cast<const uint4*>(p), f);
}
static __device__ __forceinline__ unsigned short f2bf(float x) {
    __hip_bfloat16 h = __float2bfloat16(x);
    return *reinterpret_cast<unsigned short*>(&h);
}
static __device__ __forceinline__ unsigned addpack(unsigned s, unsigned a) {
    float s0 = bfbits2f(s << 16), s1 = bfbits2f(s & 0xffff0000u);
    float a0 = bfbits2f(a << 16), a1 = bfbits2f(a & 0xffff0000u);
    unsigned r0 = f2bf(s0 + a0), r1 = f2bf(s1 + a1);
    return r0 | (r1 << 16);
}
static __device__ __forceinline__ uint4 pack8(const float* f) {
    uint4 u;
    u.x = (unsigned)f2bf(f[0]) | ((unsigned)f2bf(f[1]) << 16);
    u.y = (unsigned)f2bf(f[2]) | ((unsigned)f2bf(f[3]) << 16);
    u.z = (unsigned)f2bf(f[4]) | ((unsigned)f2bf(f[5]) << 16);
    u.w = (unsigned)f2bf(f[6]) | ((unsigned)f2bf(f[7]) << 16);
    return u;
}

// Fragment-swizzled layout for a [rows][K] bf16 operand of mfma_f32_16x16x32_bf16:
//   element (row, k) lives at ((panel*NQ + q)*64 + kgrp*16 + r)*8 + j
//   panel=row>>4, r=row&15, q=k>>5, kgrp=(k>>3)&3, j=k&7

// ================= node sort by n_states (descending), counting sort =================
__global__ void k_zero(int* p) { p[blockIdx.x * blockDim.x + threadIdx.x] = 0; }
__global__ void k_bcount(const int* __restrict__ nst, int* __restrict__ bcnt) {
    int n = blockIdx.x * blockDim.x + threadIdx.x;
    atomicAdd(&bcnt[10 - nst[n]], 1);   // bucket 0 = n_states 10 ... bucket 9 = n_states 1
}
__global__ void k_bprefix(const int* __restrict__ bcnt, int* __restrict__ bcur,
                          int* __restrict__ cntAct) {
    if (threadIdx.x == 0) {
        int boffs[11]; int run = 0;
        for (int b = 0; b < 10; ++b) { boffs[b] = run; run += bcnt[b]; }
        boffs[10] = run;
        for (int b = 0; b < 10; ++b) bcur[b] = boffs[b];
        for (int i = 0; i < 10; ++i) cntAct[i] = boffs[10 - i];  // #nodes with ns > i
    }
}
__global__ void k_bscatter(const int* __restrict__ nst, int* __restrict__ bcur,
                           int* __restrict__ perm, int* __restrict__ inv) {
    int n = blockIdx.x * blockDim.x + threadIdx.x;
    int pos = atomicAdd(&bcur[10 - nst[n]], 1);
    perm[pos] = n; inv[n] = pos;
}

// ================= weight composition / packing (unchanged from R8) =================
__global__ __launch_bounds__(256) void k_comp_eam(const float* __restrict__ We,
                                                  const float* __restrict__ Wa,
                                                  const float* __restrict__ Wm,
                                                  ushort_t* __restrict__ out) {
    __shared__ float w_lds[128][17];
    const int t = threadIdx.x;
    const int p = blockIdx.x;          // 64 panels
    const int cl = t & 15, kbase = t >> 4;
    const int c = p * 16 + cl;
#pragma unroll
    for (int i = 0; i < 8; ++i) {
        int kk = kbase + i * 16;
        w_lds[kk][cl] = (c < 512) ? Wa[(256 + kk) * HID4 + c] : Wm[kk * HID4 + (c - 512)];
    }
    __syncthreads();
    const int k = t >> 4;
    float s = 0.f;
    for (int kk = 0; kk < 128; ++kk)
        s = fmaf(We[k * 128 + kk], w_lds[kk][cl], s);
    int l = ((k >> 3) << 4) + cl, j = k & 7;
    out[((size_t)(p * 64 + l)) * 8 + j] = f2bf(s);
    if (t < 32) {
        uint4 z = {0, 0, 0, 0};
        *(uint4*)(out + ((size_t)(p * 64 + 32 + t)) * 8) = z;
    }
}

__global__ __launch_bounds__(256) void k_comp_fix(const float* __restrict__ Wh,
                                                  const float* __restrict__ Wa,
                                                  const float* __restrict__ Wm,
                                                  ushort_t* __restrict__ out) {
    __shared__ float w_lds[128][17];
    const int t = threadIdx.x;
    const int p = blockIdx.x;          // 96 panels
    const int cl = t & 15, kbase = t >> 4;
    const int c = p * 16 + cl;
#pragma unroll
    for (int i = 0; i < 8; ++i) {
        int kk = kbase + i * 16;
        w_lds[kk][cl] = (c < 512) ? Wa[(128 + kk) * HID4 + c]
                      : (c < 1024) ? Wa[(512 + kk) * HID4 + (c - 512)]
                                   : Wm[(256 + kk) * HID4 + (c - 1024)];
    }
    __syncthreads();
    const int k1 = t >> 4, k2 = k1 + 16;
    float s1 = 0.f, s2 = 0.f;
    for (int kk = 0; kk < 128; ++kk) {
        float wv = w_lds[kk][cl];
        s1 = fmaf(Wh[k1 * 128 + kk], wv, s1);
        s2 = fmaf(Wh[k2 * 128 + kk], wv, s2);
    }
    int l1 = ((k1 >> 3) << 4) + cl, j1 = k1 & 7;
    int l2 = ((k2 >> 3) << 4) + cl, j2 = k2 & 7;
    out[((size_t)(p * 64 + l1)) * 8 + j1] = f2bf(s1);
    out[((size_t)(p * 64 + l2)) * 8 + j2] = f2bf(s2);
}

__global__ void k_pack_var(const float* __restrict__ Wa, const float* __restrict__ Wm,
                           ushort_t* __restrict__ out) {
    int idx = blockIdx.x * blockDim.x + threadIdx.x;   // 96 panels * 4 q * 64 lanes
    int p = idx >> 8, rem = idx & 255;
    int q = rem >> 6, l = rem & 63;
    int c = p * 16 + (l & 15);
    int k0 = q * 32 + ((l >> 4) << 3);
    float v[8];
#pragma unroll
    for (int j = 0; j < 8; ++j) {
        int k = k0 + j;
        v[j] = (c < 512) ? Wa[k * HID4 + c]
             : (c < 1024) ? Wa[(384 + k) * HID4 + (c - 512)]
                          : Wm[(128 + k) * HID4 + (c - 1024)];
    }
    *(uint4*)(out + (size_t)idx * 8) = pack8(v);
}

// ---- efp_sw in CSR-EDGE ORDER: row q <- ef[eids[q]], swizzled, pad32
__global__ void k_prep_ef(const float* __restrict__ ef, const int* __restrict__ eids,
                          ushort_t* __restrict__ out) {
    int idx = blockIdx.x * blockDim.x + threadIdx.x;   // 2048 panels * 64 lanes
    int p = idx >> 6, l = idx & 63;
    int e = eids[p * 16 + (l & 15)];
    int k0 = (l >> 4) << 3;
    float v[8];
#pragma unroll
    for (int j = 0; j < 8; ++j) {
        int k = k0 + j;
        v[j] = (k < 16) ? ef[e * EFEAT + k] : 0.f;
    }
    *(uint4*)(out + (size_t)idx * 8) = pack8(v);
}

// ---- nfp_sw in PERMUTED node order: row r <- nf[perm[r]]
__global__ void k_prep_nf(const float* __restrict__ nf, const int* __restrict__ perm,
                          ushort_t* __restrict__ out) {
    int idx = blockIdx.x * blockDim.x + threadIdx.x;   // 256 panels * 64 lanes
    int p = idx >> 6, l = idx & 63;
    int n = perm[p * 16 + (l & 15)];
    int k0 = (l >> 4) << 3;
    float v[8];
#pragma unroll
    for (int j = 0; j < 8; ++j) v[j] = nf[n * NFEAT + k0 + j];
    *(uint4*)(out + (size_t)idx * 8) = pack8(v);
}

// ---- h0: permuted row = inv[n]; f32 natural + bf16 swizzled (in-place buffers)
__global__ void k_h0(const float* __restrict__ nf, const float* __restrict__ Wh,
                     const int* __restrict__ inv,
                     float* __restrict__ h, ushort_t* __restrict__ hbf) {
    int idx = blockIdx.x * blockDim.x + threadIdx.x;   // N*HID
    int n = idx >> 7, c = idx & 127;
    float s = 0.f;
#pragma unroll
    for (int k = 0; k < NFEAT; ++k) s += nf[n * NFEAT + k] * Wh[k * HIDD + c];
    int row = inv[n];
    h[(size_t)row * HIDD + c] = s;
    int p = row >> 4, r = row & 15, q = c >> 5, kg = (c >> 3) & 3, j = c & 7;
    hbf[(size_t)(((p * 4 + q) * 64) + kg * 16 + r) * 8 + j] = f2bf(s);
}

__global__ void k_mask(const float* __restrict__ ef, int* __restrict__ mask) {
    int e = blockIdx.x * blockDim.x + threadIdx.x;
    int m = 0;
#pragma unroll
    for (int k = 0; k < EFEAT; ++k) m |= (ef[e * EFEAT + k] != 0.f);
    mask[e] = m;
}

// ================= CSR build in permuted node space =================
__global__ void k_count(const int* __restrict__ src, const int* __restrict__ inv,
                        int* __restrict__ deg) {
    int e = blockIdx.x * blockDim.x + threadIdx.x;
    atomicAdd(&deg[inv[src[e]]], 1);
}
__global__ __launch_bounds__(1024) void k_scan(const int* __restrict__ deg,
                                               int* __restrict__ offs, int* __restrict__ cursor) {
    __shared__ int sm[1024];
    int t = threadIdx.x;
    int d0 = deg[t * 4], d1 = deg[t * 4 + 1], d2 = deg[t * 4 + 2], d3 = deg[t * 4 + 3];
    int s = d0 + d1 + d2 + d3;
    sm[t] = s; __syncthreads();
    for (int o = 1; o < 1024; o <<= 1) {
        int v = (t >= o) ? sm[t - o] : 0;
        __syncthreads();
        sm[t] += v;
        __syncthreads();
    }
    int run = sm[t] - s;
    offs[t * 4] = run;     cursor[t * 4] = run;     run += d0;
    offs[t * 4 + 1] = run; cursor[t * 4 + 1] = run; run += d1;
    offs[t * 4 + 2] = run; cursor[t * 4 + 2] = run; run += d2;
    offs[t * 4 + 3] = run; cursor[t * 4 + 3] = run;
    if (t == 1023) offs[4096] = run + d3;
}
__global__ void k_fill(const int* __restrict__ src, const int* __restrict__ inv,
                       int* __restrict__ cursor, int* __restrict__ eids) {
    int e = blockIdx.x * blockDim.x + threadIdx.x;
    int pos = atomicAdd(&cursor[inv[src[e]]], 1);
    eids[pos] = e;
}
// per-CSR-slot target (permuted) + mask
__global__ void k_tgtp(const int* __restrict__ eids, const int* __restrict__ tgt,
                       const int* __restrict__ inv, const int* __restrict__ mask,
                       int* __restrict__ tgtp, int* __restrict__ maskp) {
    int q = blockIdx.x * blockDim.x + threadIdx.x;
    int e = eids[q];
    tgtp[q] = inv[tgt[e]];
    maskp[q] = mask[e];
}

// ================= K=32 swizzled GEMM (setup) =================
__global__ __launch_bounds__(256) void k_gemm32(const ushort_t* __restrict__ A_sw,
                                                const ushort_t* __restrict__ B_sw,
                                                ushort_t* __restrict__ C, int NC) {
    __shared__ ushort_t lds[4][64][64];
    const int tid = threadIdx.x;
    const int l = tid & 63;
    const int w = tid >> 6;
    const int mpb = blockIdx.y * 16 + w * 4;
    const int cpb = blockIdx.x * 4;

    bf16x8 a[4], b[4];
#pragma unroll
    for (int mi = 0; mi < 4; ++mi)
        a[mi] = *(const bf16x8*)(A_sw + (size_t)((mpb + mi) * 64 + l) * 8);
#pragma unroll
    for (int ct = 0; ct < 4; ++ct)
        b[ct] = *(const bf16x8*)(B_sw + (size_t)((cpb + ct) * 64 + l) * 8);

    const int rb = (l >> 4) << 2, lc = l & 15;
#pragma unroll
    for (int mi = 0; mi < 4; ++mi)
#pragma unroll
        for (int ct = 0; ct < 4; ++ct) {
            f32x4 c = {0.f, 0.f, 0.f, 0.f};
            c = __builtin_amdgcn_mfma_f32_16x16x32_bf16(a[mi], b[ct], c, 0, 0, 0);
#pragma unroll
            for (int r = 0; r < 4; ++r)
                lds[w][mi * 16 + rb + r][ct * 16 + lc] = f2bf(c[r]);
        }
    __syncthreads();
#pragma unroll
    for (int i = 0; i < 8; ++i) {
        int ch = (i << 6) + l;
        int row = ch >> 3, co = (ch & 7) << 3;
        int grow = blockIdx.y * 256 + w * 64 + row;
        size_t gidx = (size_t)grow * NC + blockIdx.x * 64 + co;
        *(uint4*)(C + gidx) = *(const uint4*)(&lds[w][row][co]);
    }
}

// ================= K=128 swizzled GEMM + Cadd, with frozen-prefix block skip =================
// Skip threshold: cntAct[iter-1] (a node's Tcur must be recomputed once more on its
// first frozen iteration, since h changed at its last active iteration).
__global__ __launch_bounds__(256) void k_gemm128(const ushort_t* __restrict__ A_sw,
                                                 const ushort_t* __restrict__ B_sw,
                                                 const ushort_t* __restrict__ Cadd,
                                                 ushort_t* __restrict__ C, int NC,
                                                 const int* __restrict__ cntAct, int iter) {
    const int thr = (iter == 0) ? N_NODES : cntAct[iter - 1];
    if ((int)(blockIdx.y * 128) >= thr) return;

    __shared__ ushort_t lds[4][32][64];
    const int tid = threadIdx.x;
    const int l = tid & 63;
    const int w = tid >> 6;
    const int mpb = blockIdx.y * 8 + w * 2;
    const int cpb = blockIdx.x * 4;

    bf16x8 a[2][4], b[4][4];
#pragma unroll
    for (int mi = 0; mi < 2; ++mi)
#pragma unroll
        for (int q = 0; q < 4; ++q)
            a[mi][q] = *(const bf16x8*)(A_sw + (size_t)(((mpb + mi) * 4 + q) * 64 + l) * 8);
#pragma unroll
    for (int ct = 0; ct < 4; ++ct)
#pragma unroll
        for (int q = 0; q < 4; ++q)
            b[ct][q] = *(const bf16x8*)(B_sw + (size_t)(((cpb + ct) * 4 + q) * 64 + l) * 8);

    const int rb = (l >> 4) << 2, lc = l & 15;
#pragma unroll
    for (int mi = 0; mi < 2; ++mi)
#pragma unroll
        for (int ct = 0; ct < 4; ++ct) {
            f32x4 c = {0.f, 0.f, 0.f, 0.f};
#pragma unroll
            for (int q = 0; q < 4; ++q)
                c = __builtin_amdgcn_mfma_f32_16x16x32_bf16(a[mi][q], b[ct][q], c, 0, 0, 0);
#pragma unroll
            for (int r = 0; r < 4; ++r)
                lds[w][mi * 16 + rb + r][ct * 16 + lc] = f2bf(c[r]);
        }
    __syncthreads();
#pragma unroll
    for (int i = 0; i < 4; ++i) {
        int ch = (i << 6) + l;
        int row = ch >> 3, co = (ch & 7) << 3;
        int grow = blockIdx.y * 128 + w * 32 + row;
        size_t gidx = (size_t)grow * NC + blockIdx.x * 64 + co;
        uint4 sv = *(const uint4*)(&lds[w][row][co]);
        uint4 av = *(const uint4*)(Cadd + gidx);
        sv.x = addpack(sv.x, av.x);
        sv.y = addpack(sv.y, av.y);
        sv.z = addpack(sv.z, av.z);
        sv.w = addpack(sv.w, av.w);
        *(uint4*)(C + gidx) = sv;
    }
}

// ================= fused edge pass: permuted nodes, CSR-ordered edges, in-place h =====
__global__ __launch_bounds__(256) void k_edge(const ushort_t* __restrict__ T,    // [N][1536] bf16 (permuted rows)
                                              const ushort_t* __restrict__ eam,  // [E][1024] bf16 (CSR order)
                                              const int* __restrict__ tgtp,      // [E] permuted tgt per CSR slot
                                              const int* __restrict__ offs,
                                              const int* __restrict__ maskp,
                                              const float* __restrict__ a_kern,
                                              const int* __restrict__ cntAct,
                                              float* __restrict__ h,
                                              ushort_t* __restrict__ hbf, int iter) {
    const int n = (blockIdx.x << 2) + (threadIdx.x >> 6);
    if (n >= cntAct[iter]) return;     // frozen prefix-exit: h row untouched (in-place)

    const int lane = threadIdx.x & 63;
    const int c0 = lane << 3;
    const int e0 = offs[n], e1 = offs[n + 1];

    float ak[8];
    {
        const float4* p = reinterpret_cast<const float4*>(a_kern + ((lane & 15) << 3));
        float4 a0 = p[0], a1 = p[1];
        ak[0] = a0.x; ak[1] = a0.y; ak[2] = a0.z; ak[3] = a0.w;
        ak[4] = a1.x; ak[5] = a1.y; ak[6] = a1.z; ak[7] = a1.w;
    }
    float asrc[8];
    load8bf(T + (size_t)n * TVAR + c0, asrc);

    float m = -INFINITY, s = 0.f;
    float acc[8] = {0, 0, 0, 0, 0, 0, 0, 0};

    int mk_n = 0;
    uint4 va_n, vt_n, vm_n, vtm_n;
    if (e0 < e1) {
        int t = tgtp[e0]; mk_n = maskp[e0];
        va_n  = *(const uint4*)(eam + (size_t)e0 * 1024 + c0);
        vt_n  = *(const uint4*)(T + (size_t)t * TVAR + 512 + c0);
        vm_n  = *(const uint4*)(eam + (size_t)e0 * 1024 + 512 + c0);
        vtm_n = *(const uint4*)(T + (size_t)t * TVAR + 1024 + c0);
    }
    for (int q = e0; q < e1; ++q) {
        uint4 va = va_n, vt = vt_n, vm = vm_n, vtm = vtm_n;
        int mk = mk_n;
        int q2 = q + 1;
        if (q2 < e1) {
            int t = tgtp[q2]; mk_n = maskp[q2];
            va_n  = *(const uint4*)(eam + (size_t)q2 * 1024 + c0);
            vt_n  = *(const uint4*)(T + (size_t)t * TVAR + 512 + c0);
            vm_n  = *(const uint4*)(eam + (size_t)q2 * 1024 + 512 + c0);
            vtm_n = *(const uint4*)(T + (size_t)t * TVAR + 1024 + c0);
        }
        float ea[8], tt[8], em[8], tm[8];
        unpack8(va, ea); unpack8(vt, tt); unpack8(vm, em); unpack8(vtm, tm);
        float p = 0.f;
#pragma unroll
        for (int j = 0; j < 8; ++j) {
            float v = asrc[j] + ea[j] + tt[j];
            v = (v > 0.f) ? v : 0.2f * v;          // leaky_relu 0.2
            p = fmaf(v, ak[j], p);
        }
        p += __shfl_xor(p, 1);
        p += __shfl_xor(p, 2);
        p += __shfl_xor(p, 4);
        p += __shfl_xor(p, 8);                     // per-head logit (16-lane group)
        p = mk ? p : -INFINITY;
        float mn = fmaxf(m, p);
        bool live = (mn != -INFINITY);
        float wgt = live ? __expf(p - mn) : 0.f;
        float sc  = live ? __expf(m - mn) : 0.f;
        s = s * sc + wgt;
#pragma unroll
        for (int j = 0; j < 8; ++j) acc[j] = acc[j] * sc + wgt * (em[j] + tm[j]);
        m = mn;
    }
    if (e1 > e0 && m == -INFINITY) {
        // dead node (all edges masked): uniform attention over ALL its edges
        s = (float)(e1 - e0);
        for (int q = e0; q < e1; ++q) {
            int t = tgtp[q];
            float em[8], tm[8];
            load8bf(eam + (size_t)q * 1024 + 512 + c0, em);
            load8bf(T + (size_t)t * TVAR + 1024 + c0, tm);
#pragma unroll
            for (int j = 0; j < 8; ++j) acc[j] += em[j] + tm[j];
        }
    }
    float inv_s = (e1 > e0) ? (1.f / s) : 0.f;
    float r[8];
#pragma unroll
    for (int j = 0; j < 8; ++j) {
        float v = acc[j] * inv_s;
        v += __shfl_xor(v, 16);
        v += __shfl_xor(v, 32);
        r[j] = v;
    }
    if (lane < 16) {
        float out[8];
#pragma unroll
        for (int j = 0; j < 8; ++j) out[j] = tanhf(r[j]);
        float4* ph = reinterpret_cast<float4*>(h + (size_t)n * HIDD + c0);
        float4 o0, o1;
        o0.x = out[0]; o0.y = out[1]; o0.z = out[2]; o0.w = out[3];
        o1.x = out[4]; o1.y = out[5]; o1.z = out[6]; o1.w = out[7];
        ph[0] = o0; ph[1] = o1;
        int p = n >> 4, rr = n & 15, q = lane >> 2, kg = lane & 3;
        *(uint4*)(hbf + (size_t)(((p * 4 + q) * 64) + kg * 16 + rr) * 8) = pack8(out);
    }
}

// ---------------- out = h[inv[cs]] @ W_g ----------------
__global__ void k_out(const float* __restrict__ h, const int* __restrict__ cs,
                      const int* __restrict__ inv, const float* __restrict__ Wg,
                      float* __restrict__ out) {
    int idx = blockIdx.x * blockDim.x + threadIdx.x;   // B*ENC
    int b = idx >> 6, c = idx & 63;
    int n = inv[cs[b]];
    float s = 0.f;
#pragma unroll
    for (int k = 0; k < HIDD; ++k) s += h[(size_t)n * HIDD + k] * Wg[k * ENCD + c];
    out[idx] = s;
}

extern "C" void kernel_launch(void* const* d_in, const int* in_sizes, int n_in,
                              void* d_out, int out_size, void* d_ws, size_t ws_size,
                              hipStream_t stream) {
    const float* nf  = (const float*)d_in[0];
    const float* ef  = (const float*)d_in[1];
    const int* eidx  = (const int*)d_in[2];
    const int* cs    = (const int*)d_in[3];
    const int* nst   = (const int*)d_in[4];
    const float* Wh  = (const float*)d_in[5];
    const float* We  = (const float*)d_in[6];
    const float* Wa  = (const float*)d_in[7];
    const float* Wm  = (const float*)d_in[8];
    const float* akn = (const float*)d_in[9];
    const float* Wg  = (const float*)d_in[10];
    const int* src = eidx;
    const int* tgt = eidx + N_EDGES;

    char* w = (char*)d_ws;
    size_t off = 0;
    auto alloc = [&](size_t bytes) -> void* {
        void* p = w + off;
        off = (off + bytes + 255) & ~(size_t)255;
        return p;
    };
    float* h         = (float*)alloc((size_t)N_NODES * HIDD * 4);      // in-place
    ushort_t* hbf    = (ushort_t*)alloc((size_t)N_NODES * HIDD * 2);   // in-place swizzled
    int* mask        = (int*)alloc((size_t)N_EDGES * 4);
    ushort_t* eam    = (ushort_t*)alloc((size_t)N_EDGES * 1024 * 2);   // 64 MB, CSR order
    ushort_t* Tfix   = (ushort_t*)alloc((size_t)N_NODES * TVAR * 2);   // permuted rows
    ushort_t* Tcur   = (ushort_t*)alloc((size_t)N_NODES * TVAR * 2);
    ushort_t* Wcomb  = (ushort_t*)alloc((size_t)64 * 64 * 8 * 2);
    ushort_t* WfixC  = (ushort_t*)alloc((size_t)96 * 64 * 8 * 2);
    ushort_t* WvarSw = (ushort_t*)alloc((size_t)96 * 4 * 64 * 8 * 2);
    ushort_t* efp    = (ushort_t*)alloc((size_t)2048 * 64 * 8 * 2);
    ushort_t* nfp    = (ushort_t*)alloc((size_t)256 * 64 * 8 * 2);
    int* iws         = (int*)alloc((size_t)4352 * 4);                  // deg[4096] + meta[256]
    int* deg    = iws;
    int* bcnt   = iws + 4096;
    int* bcur   = iws + 4112;
    int* cntAct = iws + 4128;
    int* offs        = (int*)alloc((size_t)(N_NODES + 1) * 4);
    int* cursor      = (int*)alloc((size_t)N_NODES * 4);
    int* perm        = (int*)alloc((size_t)N_NODES * 4);
    int* inv         = (int*)alloc((size_t)N_NODES * 4);
    int* eids        = (int*)alloc((size_t)N_EDGES * 4);
    int* tgtp        = (int*)alloc((size_t)N_EDGES * 4);
    int* maskp       = (int*)alloc((size_t)N_EDGES * 4);
    (void)ws_size; (void)in_sizes; (void)n_in; (void)out_size;  // ~96 MB used

    // ---- node sort + CSR build (permuted space) ----
    k_zero<<<17, 256, 0, stream>>>(iws);                               // deg + meta
    k_bcount<<<N_NODES / 256, 256, 0, stream>>>(nst, bcnt);
    k_bprefix<<<1, 64, 0, stream>>>(bcnt, bcur, cntAct);
    k_bscatter<<<N_NODES / 256, 256, 0, stream>>>(nst, bcur, perm, inv);
    k_mask<<<N_EDGES / 256, 256, 0, stream>>>(ef, mask);
    k_count<<<N_EDGES / 256, 256, 0, stream>>>(src, inv, deg);
    k_scan<<<1, 1024, 0, stream>>>(deg, offs, cursor);
    k_fill<<<N_EDGES / 256, 256, 0, stream>>>(src, inv, cursor, eids);
    k_tgtp<<<N_EDGES / 256, 256, 0, stream>>>(eids, tgt, inv, mask, tgtp, maskp);

    // ---- weight composition + operand prep (permuted / CSR order) ----
    k_comp_eam<<<64, 256, 0, stream>>>(We, Wa, Wm, Wcomb);
    k_comp_fix<<<96, 256, 0, stream>>>(Wh, Wa, Wm, WfixC);
    k_pack_var<<<96, 256, 0, stream>>>(Wa, Wm, WvarSw);
    k_prep_ef<<<512, 256, 0, stream>>>(ef, eids, efp);
    k_prep_nf<<<64, 256, 0, stream>>>(nf, perm, nfp);
    k_h0<<<(N_NODES * HIDD) / 256, 256, 0, stream>>>(nf, Wh, inv, h, hbf);

    // eam[q][1024] = efp @ Wcomb (K=16 padded to 32), CSR-ordered rows
    k_gemm32<<<dim3(1024 / 64, N_EDGES / 256), 256, 0, stream>>>(efp, Wcomb, eam, 1024);
    // Tfix[N][1536] = nfp @ WfixC (K=32), permuted rows
    k_gemm32<<<dim3(TVAR / 64, N_NODES / 256), 256, 0, stream>>>(nfp, WfixC, Tfix, TVAR);

    // ---- iteration loop: in-place h, frozen-prefix skipping ----
    for (int i = 0; i < MAXS; ++i) {
        k_gemm128<<<dim3(TVAR / 64, N_NODES / 128), 256, 0, stream>>>(hbf, WvarSw, Tfix, Tcur,
                                                                      TVAR, cntAct, i);
        k_edge<<<N_NODES / 4, 256, 0, stream>>>(Tcur, eam, tgtp, offs, maskp, akn, cntAct,
                                                h, hbf, i);
    }
    k_out<<<(BATCH * ENCD) / 256, 256, 0, stream>>>(h, cs, inv, Wg, (float*)d_out);
}